// Round 2
// baseline (1202.347 us; speedup 1.0000x reference)
//
#include <hip/hip_runtime.h>
#include <stdint.h>

// ---------------- problem constants ----------------
#define S_LEN 2048
#define HID   2048
#define NHEAD 16
#define HD    128     // head dim
#define NQK   8192    // concat q,k rows of [w_q; w_k]
#define K_HID 2048

typedef __bf16 bf16x8 __attribute__((ext_vector_type(8)));
typedef float  f32x4  __attribute__((ext_vector_type(4)));

__device__ __forceinline__ unsigned short f2bf(float f) {
    union { float f; uint32_t u; } c; c.f = f;
    uint32_t u = c.u;
    return (unsigned short)((u + 0x7fffu + ((u >> 16) & 1u)) >> 16);  // RNE
}
__device__ __forceinline__ float bf2f(unsigned short b) {
    union { uint32_t u; float f; } c; c.u = ((uint32_t)b) << 16;
    return c.f;
}
__device__ __forceinline__ float softplus_f(float x) {
    return (x > 20.f) ? x : log1pf(expf(x));
}

// ---------------- cast fp32 -> bf16 (single) ----------------
__global__ __launch_bounds__(256) void cast_f32_bf16(const float* __restrict__ in,
                                                     unsigned short* __restrict__ out,
                                                     int n4) {
    int i = blockIdx.x * 256 + threadIdx.x;
    if (i < n4) {
        float4 v = ((const float4*)in)[i];
        ushort4 o;
        o.x = f2bf(v.x); o.y = f2bf(v.y); o.z = f2bf(v.z); o.w = f2bf(v.w);
        ((ushort4*)out)[i] = o;
    }
}

// ---------------- cast fp32 -> bf16 hi + lo (split) ----------------
__global__ __launch_bounds__(256) void cast_split(const float* __restrict__ in,
                                                  unsigned short* __restrict__ hi,
                                                  unsigned short* __restrict__ lo,
                                                  int n4) {
    int i = blockIdx.x * 256 + threadIdx.x;
    if (i < n4) {
        float4 v = ((const float4*)in)[i];
        ushort4 h, l;
        h.x = f2bf(v.x); l.x = f2bf(v.x - bf2f(h.x));
        h.y = f2bf(v.y); l.y = f2bf(v.y - bf2f(h.y));
        h.z = f2bf(v.z); l.z = f2bf(v.z - bf2f(h.z));
        h.w = f2bf(v.w); l.w = f2bf(v.w - bf2f(h.w));
        ((ushort4*)hi)[i] = h;
        ((ushort4*)lo)[i] = l;
    }
}

// ---------------- single-bf16 NT GEMM: C[M,N] = A[M,K] * B[N,K]^T ----------
// 128x128 tile, BK=32, 256 threads = 4 waves (2x2), each wave 4x4 MFMA tiles.
// C/D layout: col = lane&15, row = (lane>>4)*4 + reg  (m89/m91 verified)
template <bool OUT_BF16>
__global__ __launch_bounds__(256) void gemm_nt(const unsigned short* __restrict__ A,
                                               const unsigned short* __restrict__ B,
                                               void* __restrict__ Cv,
                                               int M, int N, int Kd) {
    constexpr int LDT = 40;  // 32 + 8 pad
    __shared__ __align__(16) unsigned short As[128 * LDT];
    __shared__ __align__(16) unsigned short Bs[128 * LDT];
    const int t    = threadIdx.x;
    const int m0   = blockIdx.y * 128;
    const int n0   = blockIdx.x * 128;
    const int wave = t >> 6;
    const int lane = t & 63;
    const int wm   = wave >> 1, wn = wave & 1;
    const int lrow = lane & 15, quad = lane >> 4;
    const int srow = t >> 2;
    const int scol = (t & 3) * 8;

    f32x4 acc[4][4];
    for (int i = 0; i < 4; ++i)
        for (int j = 0; j < 4; ++j)
            acc[i][j] = (f32x4){0.f, 0.f, 0.f, 0.f};

    for (int k0 = 0; k0 < Kd; k0 += 32) {
        const unsigned short* Ag = A + (size_t)(m0 + srow) * Kd + k0 + scol;
        const unsigned short* Bg = B + (size_t)(n0 + srow) * Kd + k0 + scol;
        *(uint4*)(&As[srow * LDT + scol])        = *(const uint4*)Ag;
        *(uint4*)(&As[(srow + 64) * LDT + scol]) = *(const uint4*)(Ag + (size_t)64 * Kd);
        *(uint4*)(&Bs[srow * LDT + scol])        = *(const uint4*)Bg;
        *(uint4*)(&Bs[(srow + 64) * LDT + scol]) = *(const uint4*)(Bg + (size_t)64 * Kd);
        __syncthreads();

        bf16x8 af[4], bfr[4];
        for (int tm = 0; tm < 4; ++tm)
            af[tm]  = *(const bf16x8*)(&As[(wm * 64 + tm * 16 + lrow) * LDT + quad * 8]);
        for (int tn = 0; tn < 4; ++tn)
            bfr[tn] = *(const bf16x8*)(&Bs[(wn * 64 + tn * 16 + lrow) * LDT + quad * 8]);
        for (int tm = 0; tm < 4; ++tm)
            for (int tn = 0; tn < 4; ++tn)
                acc[tm][tn] = __builtin_amdgcn_mfma_f32_16x16x32_bf16(af[tm], bfr[tn], acc[tm][tn], 0, 0, 0);
        __syncthreads();
    }

    for (int tm = 0; tm < 4; ++tm)
        for (int tn = 0; tn < 4; ++tn) {
            int col = n0 + wn * 64 + tn * 16 + lrow;
            for (int r = 0; r < 4; ++r) {
                int row = m0 + wm * 64 + tm * 16 + quad * 4 + r;
                if (OUT_BF16)
                    ((unsigned short*)Cv)[(size_t)row * N + col] = f2bf(acc[tm][tn][r]);
                else
                    ((float*)Cv)[(size_t)row * N + col] = acc[tm][tn][r];
            }
        }
}

// ---------------- bf16x3 split NT GEMM (~fp32 precision), fp32 out ---------
// C = Ah*Bh^T + Al*Bh^T + Ah*Bl^T   (missing Al*Bl ~ 2^-18 relative)
__global__ __launch_bounds__(256) void gemm3_nt(const unsigned short* __restrict__ Ah,
                                                const unsigned short* __restrict__ Al,
                                                const unsigned short* __restrict__ Bh,
                                                const unsigned short* __restrict__ Bl,
                                                float* __restrict__ C,
                                                int M, int N, int Kd) {
    constexpr int LDT = 40;
    __shared__ __align__(16) unsigned short Ash[128 * LDT];
    __shared__ __align__(16) unsigned short Asl[128 * LDT];
    __shared__ __align__(16) unsigned short Bsh[128 * LDT];
    __shared__ __align__(16) unsigned short Bsl[128 * LDT];
    const int t    = threadIdx.x;
    const int m0   = blockIdx.y * 128;
    const int n0   = blockIdx.x * 128;
    const int wave = t >> 6;
    const int lane = t & 63;
    const int wm   = wave >> 1, wn = wave & 1;
    const int lrow = lane & 15, quad = lane >> 4;
    const int srow = t >> 2;
    const int scol = (t & 3) * 8;

    f32x4 acc[4][4];
    for (int i = 0; i < 4; ++i)
        for (int j = 0; j < 4; ++j)
            acc[i][j] = (f32x4){0.f, 0.f, 0.f, 0.f};

    for (int k0 = 0; k0 < Kd; k0 += 32) {
        size_t offA0 = (size_t)(m0 + srow) * Kd + k0 + scol;
        size_t offA1 = offA0 + (size_t)64 * Kd;
        size_t offB0 = (size_t)(n0 + srow) * Kd + k0 + scol;
        size_t offB1 = offB0 + (size_t)64 * Kd;
        *(uint4*)(&Ash[srow * LDT + scol])        = *(const uint4*)(Ah + offA0);
        *(uint4*)(&Ash[(srow + 64) * LDT + scol]) = *(const uint4*)(Ah + offA1);
        *(uint4*)(&Asl[srow * LDT + scol])        = *(const uint4*)(Al + offA0);
        *(uint4*)(&Asl[(srow + 64) * LDT + scol]) = *(const uint4*)(Al + offA1);
        *(uint4*)(&Bsh[srow * LDT + scol])        = *(const uint4*)(Bh + offB0);
        *(uint4*)(&Bsh[(srow + 64) * LDT + scol]) = *(const uint4*)(Bh + offB1);
        *(uint4*)(&Bsl[srow * LDT + scol])        = *(const uint4*)(Bl + offB0);
        *(uint4*)(&Bsl[(srow + 64) * LDT + scol]) = *(const uint4*)(Bl + offB1);
        __syncthreads();

        bf16x8 afh[4], afl[4], bfh[4], bfl[4];
        for (int tm = 0; tm < 4; ++tm) {
            int o = (wm * 64 + tm * 16 + lrow) * LDT + quad * 8;
            afh[tm] = *(const bf16x8*)(&Ash[o]);
            afl[tm] = *(const bf16x8*)(&Asl[o]);
        }
        for (int tn = 0; tn < 4; ++tn) {
            int o = (wn * 64 + tn * 16 + lrow) * LDT + quad * 8;
            bfh[tn] = *(const bf16x8*)(&Bsh[o]);
            bfl[tn] = *(const bf16x8*)(&Bsl[o]);
        }
        for (int tm = 0; tm < 4; ++tm)
            for (int tn = 0; tn < 4; ++tn) {
                acc[tm][tn] = __builtin_amdgcn_mfma_f32_16x16x32_bf16(afl[tm], bfh[tn], acc[tm][tn], 0, 0, 0);
                acc[tm][tn] = __builtin_amdgcn_mfma_f32_16x16x32_bf16(afh[tm], bfl[tn], acc[tm][tn], 0, 0, 0);
                acc[tm][tn] = __builtin_amdgcn_mfma_f32_16x16x32_bf16(afh[tm], bfh[tn], acc[tm][tn], 0, 0, 0);
            }
        __syncthreads();
    }

    for (int tm = 0; tm < 4; ++tm)
        for (int tn = 0; tn < 4; ++tn) {
            int col = n0 + wn * 64 + tn * 16 + lrow;
            for (int r = 0; r < 4; ++r) {
                int row = m0 + wm * 64 + tm * 16 + quad * 4 + r;
                C[(size_t)row * N + col] = acc[tm][tn][r];
            }
        }
}

// ---------------- prep: softplus + rsqrt + RoPE + key bias ----------------
// qk fp32 [S][8192]: q cols h*256 + {mu:0..127, sig:128..255}; k at +4096.
__global__ __launch_bounds__(256) void prep_qk(const float* __restrict__ qk,
                                               const float* __restrict__ cosb,
                                               const float* __restrict__ sinb,
                                               float* __restrict__ Qw,
                                               float* __restrict__ Kw,
                                               float* __restrict__ kbias) {
    int gid  = blockIdx.x * 4 + (threadIdx.x >> 6);
    int lane = threadIdx.x & 63;
    int h = gid >> 11;
    int s = gid & 2047;
    int d1 = lane, d2 = lane + 64;
    const float* row = qk + (size_t)s * NQK;
    float c1 = cosb[s * HD + d1], c2 = cosb[s * HD + d2];
    float s1 = sinb[s * HD + d1], s2 = sinb[s * HD + d2];

    {   // Q side (row constants cancel in softmax)
        int base = h * 256;
        float mu1 = row[base + d1],            mu2 = row[base + d2];
        float sg1 = softplus_f(row[base + 128 + d1]) + 1e-4f;
        float sg2 = softplus_f(row[base + 128 + d2]) + 1e-4f;
        float w1 = mu1 * rsqrtf(sg1), w2 = mu2 * rsqrtf(sg2);
        float o1 = w1 * c1 - w2 * s1;
        float o2 = w2 * c2 + w1 * s2;
        float* qrow = Qw + ((size_t)h * S_LEN + s) * HD;
        qrow[d1] = o1; qrow[d2] = o2;
    }
    {   // K side + bias = -0.5*(|kw|^2 + sum log sigma)
        int base = 4096 + h * 256;
        float mu1 = row[base + d1],            mu2 = row[base + d2];
        float sg1 = softplus_f(row[base + 128 + d1]) + 1e-4f;
        float sg2 = softplus_f(row[base + 128 + d2]) + 1e-4f;
        float w1 = mu1 * rsqrtf(sg1), w2 = mu2 * rsqrtf(sg2);
        float o1 = w1 * c1 - w2 * s1;
        float o2 = w2 * c2 + w1 * s2;
        float* krow = Kw + ((size_t)h * S_LEN + s) * HD;
        krow[d1] = o1; krow[d2] = o2;
        float part = o1 * o1 + o2 * o2 + logf(sg1) + logf(sg2);
        for (int off = 32; off > 0; off >>= 1) part += __shfl_down(part, off);
        if (lane == 0) kbias[(size_t)h * S_LEN + s] = -0.5f * part;
    }
}

// ---------------- flash attention, fp32 vector math ----------------
__global__ __launch_bounds__(256) void flash_attn(const float* __restrict__ Qw,
                                                  const float* __restrict__ Kw,
                                                  const unsigned short* __restrict__ Vb,
                                                  const float* __restrict__ kbias,
                                                  unsigned short* __restrict__ Obf) {
    constexpr int LKV = 132;
    __shared__ float Qs[64 * 128];
    __shared__ __align__(16) float Ks[32 * LKV];
    __shared__ __align__(16) float Vs[32 * LKV];
    __shared__ float Ps[64 * 33];
    __shared__ float kb[32];
    const int t  = threadIdx.x;
    const int h  = blockIdx.y;
    const int q0 = blockIdx.x * 64;
    const int tx = t & 15, ty = t >> 4;

    {   // stage Q tile once
        int r = t >> 2;
        int c0 = (t & 3) * 32;
        const float* src = Qw + ((size_t)h * S_LEN + q0 + r) * HD + c0;
        for (int i = 0; i < 8; ++i)
            *(float4*)(&Qs[r * 128 + c0 + i * 4]) = *(const float4*)(src + i * 4);
    }
    float O[4][8];
    float mrow[4], lsum[4];
    for (int i = 0; i < 4; ++i) {
        mrow[i] = -INFINITY; lsum[i] = 0.f;
        for (int c = 0; c < 8; ++c) O[i][c] = 0.f;
    }

    for (int k0 = 0; k0 < S_LEN; k0 += 32) {
        {
            int r  = t >> 3;
            int c0 = (t & 7) * 16;
            const float* ksrc = Kw + ((size_t)h * S_LEN + k0 + r) * HD + c0;
            for (int i = 0; i < 4; ++i)
                *(float4*)(&Ks[r * LKV + c0 + i * 4]) = *(const float4*)(ksrc + i * 4);
            const unsigned short* vsrc = Vb + (size_t)(k0 + r) * HID + h * HD + c0;
            for (int i = 0; i < 2; ++i) {
                uint4 p = *(const uint4*)(vsrc + i * 8);
                int b = r * LKV + c0 + i * 8;
                Vs[b + 0] = bf2f((unsigned short)(p.x & 0xffff));
                Vs[b + 1] = bf2f((unsigned short)(p.x >> 16));
                Vs[b + 2] = bf2f((unsigned short)(p.y & 0xffff));
                Vs[b + 3] = bf2f((unsigned short)(p.y >> 16));
                Vs[b + 4] = bf2f((unsigned short)(p.z & 0xffff));
                Vs[b + 5] = bf2f((unsigned short)(p.z >> 16));
                Vs[b + 6] = bf2f((unsigned short)(p.w & 0xffff));
                Vs[b + 7] = bf2f((unsigned short)(p.w >> 16));
            }
            if (t < 32) kb[t] = kbias[(size_t)h * S_LEN + k0 + t];
        }
        __syncthreads();

        float sc[4][2] = {{0.f,0.f},{0.f,0.f},{0.f,0.f},{0.f,0.f}};
        for (int dc = 0; dc < 128; dc += 4) {
            float4 qv[4], kv[2];
            for (int i = 0; i < 4; ++i) qv[i] = *(const float4*)(&Qs[(ty * 4 + i) * 128 + dc]);
            for (int j = 0; j < 2; ++j) kv[j] = *(const float4*)(&Ks[(tx * 2 + j) * LKV + dc]);
            for (int i = 0; i < 4; ++i)
                for (int j = 0; j < 2; ++j) {
                    sc[i][j] = fmaf(qv[i].x, kv[j].x, sc[i][j]);
                    sc[i][j] = fmaf(qv[i].y, kv[j].y, sc[i][j]);
                    sc[i][j] = fmaf(qv[i].z, kv[j].z, sc[i][j]);
                    sc[i][j] = fmaf(qv[i].w, kv[j].w, sc[i][j]);
                }
        }
        for (int i = 0; i < 4; ++i)
            for (int j = 0; j < 2; ++j) sc[i][j] += kb[tx * 2 + j];

        float p[4][2];
        for (int i = 0; i < 4; ++i) {
            float v = fmaxf(sc[i][0], sc[i][1]);
            v = fmaxf(v, __shfl_xor(v, 1));
            v = fmaxf(v, __shfl_xor(v, 2));
            v = fmaxf(v, __shfl_xor(v, 4));
            v = fmaxf(v, __shfl_xor(v, 8));
            float mnew  = fmaxf(mrow[i], v);
            float alpha = __expf(mrow[i] - mnew);
            mrow[i] = mnew;
            p[i][0] = __expf(sc[i][0] - mnew);
            p[i][1] = __expf(sc[i][1] - mnew);
            float rs = p[i][0] + p[i][1];
            rs += __shfl_xor(rs, 1);
            rs += __shfl_xor(rs, 2);
            rs += __shfl_xor(rs, 4);
            rs += __shfl_xor(rs, 8);
            lsum[i] = lsum[i] * alpha + rs;
            for (int c = 0; c < 8; ++c) O[i][c] *= alpha;
        }
        for (int i = 0; i < 4; ++i)
            for (int j = 0; j < 2; ++j)
                Ps[(ty * 4 + i) * 33 + tx * 2 + j] = p[i][j];
        __syncthreads();

#pragma unroll 4
        for (int kt = 0; kt < 32; ++kt) {
            float4 v0 = *(const float4*)(&Vs[kt * LKV + tx * 8]);
            float4 v1 = *(const float4*)(&Vs[kt * LKV + tx * 8 + 4]);
            for (int i = 0; i < 4; ++i) {
                float pi = Ps[(ty * 4 + i) * 33 + kt];
                O[i][0] = fmaf(pi, v0.x, O[i][0]);
                O[i][1] = fmaf(pi, v0.y, O[i][1]);
                O[i][2] = fmaf(pi, v0.z, O[i][2]);
                O[i][3] = fmaf(pi, v0.w, O[i][3]);
                O[i][4] = fmaf(pi, v1.x, O[i][4]);
                O[i][5] = fmaf(pi, v1.y, O[i][5]);
                O[i][6] = fmaf(pi, v1.z, O[i][6]);
                O[i][7] = fmaf(pi, v1.w, O[i][7]);
            }
        }
        __syncthreads();
    }

    for (int i = 0; i < 4; ++i) {
        float inv = 1.f / lsum[i];
        uint32_t w0 = f2bf(O[i][0] * inv) | ((uint32_t)f2bf(O[i][1] * inv) << 16);
        uint32_t w1 = f2bf(O[i][2] * inv) | ((uint32_t)f2bf(O[i][3] * inv) << 16);
        uint32_t w2 = f2bf(O[i][4] * inv) | ((uint32_t)f2bf(O[i][5] * inv) << 16);
        uint32_t w3 = f2bf(O[i][6] * inv) | ((uint32_t)f2bf(O[i][7] * inv) << 16);
        uint4 pk; pk.x = w0; pk.y = w1; pk.z = w2; pk.w = w3;
        int row = q0 + ty * 4 + i;
        *(uint4*)(&Obf[(size_t)row * HID + h * HD + tx * 8]) = pk;
    }
}

// ---------------- launch ----------------
extern "C" void kernel_launch(void* const* d_in, const int* in_sizes, int n_in,
                              void* d_out, int out_size, void* d_ws, size_t ws_size,
                              hipStream_t stream) {
    const float* hs   = (const float*)d_in[0];
    const float* cosb = (const float*)d_in[1];
    const float* sinb = (const float*)d_in[2];
    const float* wq   = (const float*)d_in[3];
    const float* wk   = (const float*)d_in[4];
    const float* wv   = (const float*)d_in[5];
    const float* wo   = (const float*)d_in[6];
    float* out = (float*)d_out;
    char*  ws  = (char*)d_ws;

    // ws layout with phase-lifetime aliasing (~168 MB):
    //   [0, 67.1MB):   w_qk_hi | w_qk_lo   (dead after QK GEMM)
    //                  -> reused for Qw | Kw | kbias
    //   [67.1, 134.2): qk_f32 [S][8192]
    //   [134.2, 151.0): hs_hi | hs_lo      (dead after GEMMs) -> Obf reuses hs_hi
    //   [151.0, 176.2): w_v | w_o | v_bf
    unsigned short* w_qk_hi = (unsigned short*)(ws);
    unsigned short* w_qk_lo = (unsigned short*)(ws + 33554432);
    float*          Qw      = (float*)(ws);
    float*          Kw      = (float*)(ws + 16777216);
    float*          kbias   = (float*)(ws + 33554432);
    float*          qk_f32  = (float*)(ws + 67108864);
    unsigned short* hs_hi   = (unsigned short*)(ws + 134217728);
    unsigned short* hs_lo   = (unsigned short*)(ws + 142606336);
    unsigned short* Obf     = (unsigned short*)(ws + 134217728);  // aliases hs_hi
    unsigned short* w_v     = (unsigned short*)(ws + 150994944);
    unsigned short* w_o     = (unsigned short*)(ws + 159383552);
    unsigned short* v_bf    = (unsigned short*)(ws + 167772160);

    // casts
    {
        int n4 = (S_LEN * HID) / 4;
        cast_split<<<(n4 + 255) / 256, 256, 0, stream>>>(hs, hs_hi, hs_lo, n4);
    }
    {
        int n4 = (4096 * K_HID) / 4;
        cast_split<<<(n4 + 255) / 256, 256, 0, stream>>>(wq, w_qk_hi, w_qk_lo, n4);
        cast_split<<<(n4 + 255) / 256, 256, 0, stream>>>(
            wk, w_qk_hi + (size_t)4096 * K_HID, w_qk_lo + (size_t)4096 * K_HID, n4);
    }
    {
        int n4 = (HID * K_HID) / 4;
        cast_f32_bf16<<<(n4 + 255) / 256, 256, 0, stream>>>(wv, w_v, n4);
        cast_f32_bf16<<<(n4 + 255) / 256, 256, 0, stream>>>(wo, w_o, n4);
    }

    // QK projection, bf16x3 -> fp32  [2048, 8192]
    gemm3_nt<<<dim3(64, 16), 256, 0, stream>>>(hs_hi, hs_lo, w_qk_hi, w_qk_lo,
                                               qk_f32, S_LEN, NQK, K_HID);
    // V projection, single bf16 -> bf16  [2048, 2048]
    gemm_nt<true><<<dim3(16, 16), 256, 0, stream>>>(hs_hi, w_v, v_bf, S_LEN, HID, K_HID);
    // softplus / rsqrt / RoPE / key bias  (overwrites dead w_qk region)
    prep_qk<<<(NHEAD * S_LEN) / 4, 256, 0, stream>>>(qk_f32, cosb, sinb, Qw, Kw, kbias);
    // flash attention (fp32 vector math)
    flash_attn<<<dim3(S_LEN / 64, NHEAD), 256, 0, stream>>>(Qw, Kw, v_bf, kbias, Obf);
    // output projection: out = Obf @ w_o^T (fp32 out)
    gemm_nt<false><<<dim3(16, 16), 256, 0, stream>>>(Obf, w_o, out, S_LEN, HID, K_HID);
}

// Round 3
// 706.417 us; speedup vs baseline: 1.7020x; 1.7020x over previous
//
#include <hip/hip_runtime.h>
#include <stdint.h>

// ---------------- problem constants ----------------
#define S_LEN 2048
#define HID   2048
#define NHEAD 16
#define HD    128     // head dim
#define NQK   8192    // concat q,k rows of [w_q; w_k]
#define K_HID 2048

typedef __bf16 bf16x8 __attribute__((ext_vector_type(8)));
typedef float  f32x4  __attribute__((ext_vector_type(4)));

__device__ __forceinline__ unsigned short f2bf(float f) {
    union { float f; uint32_t u; } c; c.f = f;
    uint32_t u = c.u;
    return (unsigned short)((u + 0x7fffu + ((u >> 16) & 1u)) >> 16);  // RNE
}
__device__ __forceinline__ float bf2f(unsigned short b) {
    union { uint32_t u; float f; } c; c.u = ((uint32_t)b) << 16;
    return c.f;
}
__device__ __forceinline__ float softplus_f(float x) {
    return (x > 20.f) ? x : log1pf(expf(x));
}

// ---------------- cast fp32 -> bf16 (single) ----------------
__global__ __launch_bounds__(256) void cast_f32_bf16(const float* __restrict__ in,
                                                     unsigned short* __restrict__ out,
                                                     int n4) {
    int i = blockIdx.x * 256 + threadIdx.x;
    if (i < n4) {
        float4 v = ((const float4*)in)[i];
        ushort4 o;
        o.x = f2bf(v.x); o.y = f2bf(v.y); o.z = f2bf(v.z); o.w = f2bf(v.w);
        ((ushort4*)out)[i] = o;
    }
}

// ---------------- cast fp32 -> bf16 hi + lo (split) ----------------
__global__ __launch_bounds__(256) void cast_split(const float* __restrict__ in,
                                                  unsigned short* __restrict__ hi,
                                                  unsigned short* __restrict__ lo,
                                                  int n4) {
    int i = blockIdx.x * 256 + threadIdx.x;
    if (i < n4) {
        float4 v = ((const float4*)in)[i];
        ushort4 h, l;
        h.x = f2bf(v.x); l.x = f2bf(v.x - bf2f(h.x));
        h.y = f2bf(v.y); l.y = f2bf(v.y - bf2f(h.y));
        h.z = f2bf(v.z); l.z = f2bf(v.z - bf2f(h.z));
        h.w = f2bf(v.w); l.w = f2bf(v.w - bf2f(h.w));
        ((ushort4*)hi)[i] = h;
        ((ushort4*)lo)[i] = l;
    }
}

// ---------------- single-bf16 NT GEMM: C[M,N] = A[M,K] * B[N,K]^T ----------
// C/D layout: col = lane&15, row = (lane>>4)*4 + reg  (harness-verified)
template <bool OUT_BF16>
__global__ __launch_bounds__(256) void gemm_nt(const unsigned short* __restrict__ A,
                                               const unsigned short* __restrict__ B,
                                               void* __restrict__ Cv,
                                               int M, int N, int Kd) {
    constexpr int LDT = 40;
    __shared__ __align__(16) unsigned short As[128 * LDT];
    __shared__ __align__(16) unsigned short Bs[128 * LDT];
    const int t    = threadIdx.x;
    const int m0   = blockIdx.y * 128;
    const int n0   = blockIdx.x * 128;
    const int wave = t >> 6;
    const int lane = t & 63;
    const int wm   = wave >> 1, wn = wave & 1;
    const int lrow = lane & 15, quad = lane >> 4;
    const int srow = t >> 2;
    const int scol = (t & 3) * 8;

    f32x4 acc[4][4];
    for (int i = 0; i < 4; ++i)
        for (int j = 0; j < 4; ++j)
            acc[i][j] = (f32x4){0.f, 0.f, 0.f, 0.f};

    for (int k0 = 0; k0 < Kd; k0 += 32) {
        const unsigned short* Ag = A + (size_t)(m0 + srow) * Kd + k0 + scol;
        const unsigned short* Bg = B + (size_t)(n0 + srow) * Kd + k0 + scol;
        *(uint4*)(&As[srow * LDT + scol])        = *(const uint4*)Ag;
        *(uint4*)(&As[(srow + 64) * LDT + scol]) = *(const uint4*)(Ag + (size_t)64 * Kd);
        *(uint4*)(&Bs[srow * LDT + scol])        = *(const uint4*)Bg;
        *(uint4*)(&Bs[(srow + 64) * LDT + scol]) = *(const uint4*)(Bg + (size_t)64 * Kd);
        __syncthreads();

        bf16x8 af[4], bfr[4];
        for (int tm = 0; tm < 4; ++tm)
            af[tm]  = *(const bf16x8*)(&As[(wm * 64 + tm * 16 + lrow) * LDT + quad * 8]);
        for (int tn = 0; tn < 4; ++tn)
            bfr[tn] = *(const bf16x8*)(&Bs[(wn * 64 + tn * 16 + lrow) * LDT + quad * 8]);
        for (int tm = 0; tm < 4; ++tm)
            for (int tn = 0; tn < 4; ++tn)
                acc[tm][tn] = __builtin_amdgcn_mfma_f32_16x16x32_bf16(af[tm], bfr[tn], acc[tm][tn], 0, 0, 0);
        __syncthreads();
    }

    for (int tm = 0; tm < 4; ++tm)
        for (int tn = 0; tn < 4; ++tn) {
            int col = n0 + wn * 64 + tn * 16 + lrow;
            for (int r = 0; r < 4; ++r) {
                int row = m0 + wm * 64 + tm * 16 + quad * 4 + r;
                if (OUT_BF16)
                    ((unsigned short*)Cv)[(size_t)row * N + col] = f2bf(acc[tm][tn][r]);
                else
                    ((float*)Cv)[(size_t)row * N + col] = acc[tm][tn][r];
            }
        }
}

// ---------------- bf16x3 split NT GEMM (~fp32 precision), fp32 out ---------
__global__ __launch_bounds__(256) void gemm3_nt(const unsigned short* __restrict__ Ah,
                                                const unsigned short* __restrict__ Al,
                                                const unsigned short* __restrict__ Bh,
                                                const unsigned short* __restrict__ Bl,
                                                float* __restrict__ C,
                                                int M, int N, int Kd) {
    constexpr int LDT = 40;
    __shared__ __align__(16) unsigned short Ash[128 * LDT];
    __shared__ __align__(16) unsigned short Asl[128 * LDT];
    __shared__ __align__(16) unsigned short Bsh[128 * LDT];
    __shared__ __align__(16) unsigned short Bsl[128 * LDT];
    const int t    = threadIdx.x;
    const int m0   = blockIdx.y * 128;
    const int n0   = blockIdx.x * 128;
    const int wave = t >> 6;
    const int lane = t & 63;
    const int wm   = wave >> 1, wn = wave & 1;
    const int lrow = lane & 15, quad = lane >> 4;
    const int srow = t >> 2;
    const int scol = (t & 3) * 8;

    f32x4 acc[4][4];
    for (int i = 0; i < 4; ++i)
        for (int j = 0; j < 4; ++j)
            acc[i][j] = (f32x4){0.f, 0.f, 0.f, 0.f};

    for (int k0 = 0; k0 < Kd; k0 += 32) {
        size_t offA0 = (size_t)(m0 + srow) * Kd + k0 + scol;
        size_t offA1 = offA0 + (size_t)64 * Kd;
        size_t offB0 = (size_t)(n0 + srow) * Kd + k0 + scol;
        size_t offB1 = offB0 + (size_t)64 * Kd;
        *(uint4*)(&Ash[srow * LDT + scol])        = *(const uint4*)(Ah + offA0);
        *(uint4*)(&Ash[(srow + 64) * LDT + scol]) = *(const uint4*)(Ah + offA1);
        *(uint4*)(&Asl[srow * LDT + scol])        = *(const uint4*)(Al + offA0);
        *(uint4*)(&Asl[(srow + 64) * LDT + scol]) = *(const uint4*)(Al + offA1);
        *(uint4*)(&Bsh[srow * LDT + scol])        = *(const uint4*)(Bh + offB0);
        *(uint4*)(&Bsh[(srow + 64) * LDT + scol]) = *(const uint4*)(Bh + offB1);
        *(uint4*)(&Bsl[srow * LDT + scol])        = *(const uint4*)(Bl + offB0);
        *(uint4*)(&Bsl[(srow + 64) * LDT + scol]) = *(const uint4*)(Bl + offB1);
        __syncthreads();

        bf16x8 afh[4], afl[4], bfh[4], bfl[4];
        for (int tm = 0; tm < 4; ++tm) {
            int o = (wm * 64 + tm * 16 + lrow) * LDT + quad * 8;
            afh[tm] = *(const bf16x8*)(&Ash[o]);
            afl[tm] = *(const bf16x8*)(&Asl[o]);
        }
        for (int tn = 0; tn < 4; ++tn) {
            int o = (wn * 64 + tn * 16 + lrow) * LDT + quad * 8;
            bfh[tn] = *(const bf16x8*)(&Bsh[o]);
            bfl[tn] = *(const bf16x8*)(&Bsl[o]);
        }
        for (int tm = 0; tm < 4; ++tm)
            for (int tn = 0; tn < 4; ++tn) {
                acc[tm][tn] = __builtin_amdgcn_mfma_f32_16x16x32_bf16(afl[tm], bfh[tn], acc[tm][tn], 0, 0, 0);
                acc[tm][tn] = __builtin_amdgcn_mfma_f32_16x16x32_bf16(afh[tm], bfl[tn], acc[tm][tn], 0, 0, 0);
                acc[tm][tn] = __builtin_amdgcn_mfma_f32_16x16x32_bf16(afh[tm], bfh[tn], acc[tm][tn], 0, 0, 0);
            }
        __syncthreads();
    }

    for (int tm = 0; tm < 4; ++tm)
        for (int tn = 0; tn < 4; ++tn) {
            int col = n0 + wn * 64 + tn * 16 + lrow;
            for (int r = 0; r < 4; ++r) {
                int row = m0 + wm * 64 + tm * 16 + quad * 4 + r;
                C[(size_t)row * N + col] = acc[tm][tn][r];
            }
        }
}

// ---------------- prep: softplus + rsqrt + RoPE; emits split-bf16 Q/K ------
__global__ __launch_bounds__(256) void prep_qk(const float* __restrict__ qk,
                                               const float* __restrict__ cosb,
                                               const float* __restrict__ sinb,
                                               unsigned short* __restrict__ Qh,
                                               unsigned short* __restrict__ Ql,
                                               unsigned short* __restrict__ Kh,
                                               unsigned short* __restrict__ Kl,
                                               float* __restrict__ kbias) {
    int gid  = blockIdx.x * 4 + (threadIdx.x >> 6);
    int lane = threadIdx.x & 63;
    int h = gid >> 11;
    int s = gid & 2047;
    int d1 = lane, d2 = lane + 64;
    const float* row = qk + (size_t)s * NQK;
    float c1 = cosb[s * HD + d1], c2 = cosb[s * HD + d2];
    float s1 = sinb[s * HD + d1], s2 = sinb[s * HD + d2];
    size_t ob = ((size_t)h * S_LEN + s) * HD;

    {   // Q side (row constants cancel in softmax)
        int base = h * 256;
        float mu1 = row[base + d1],            mu2 = row[base + d2];
        float sg1 = softplus_f(row[base + 128 + d1]) + 1e-4f;
        float sg2 = softplus_f(row[base + 128 + d2]) + 1e-4f;
        float w1 = mu1 * rsqrtf(sg1), w2 = mu2 * rsqrtf(sg2);
        float o1 = w1 * c1 - w2 * s1;
        float o2 = w2 * c2 + w1 * s2;
        unsigned short h1 = f2bf(o1), h2 = f2bf(o2);
        Qh[ob + d1] = h1; Ql[ob + d1] = f2bf(o1 - bf2f(h1));
        Qh[ob + d2] = h2; Ql[ob + d2] = f2bf(o2 - bf2f(h2));
    }
    {   // K side + bias = -0.5*(|kw|^2 + sum log sigma)
        int base = 4096 + h * 256;
        float mu1 = row[base + d1],            mu2 = row[base + d2];
        float sg1 = softplus_f(row[base + 128 + d1]) + 1e-4f;
        float sg2 = softplus_f(row[base + 128 + d2]) + 1e-4f;
        float w1 = mu1 * rsqrtf(sg1), w2 = mu2 * rsqrtf(sg2);
        float o1 = w1 * c1 - w2 * s1;
        float o2 = w2 * c2 + w1 * s2;
        unsigned short h1 = f2bf(o1), h2 = f2bf(o2);
        Kh[ob + d1] = h1; Kl[ob + d1] = f2bf(o1 - bf2f(h1));
        Kh[ob + d2] = h2; Kl[ob + d2] = f2bf(o2 - bf2f(h2));
        float part = o1 * o1 + o2 * o2 + logf(sg1) + logf(sg2);
        for (int off = 32; off > 0; off >>= 1) part += __shfl_down(part, off);
        if (lane == 0) kbias[(size_t)h * S_LEN + s] = -0.5f * part;
    }
}

// ---------------- flash attention, MFMA ----------------
// Block 256 thr = 4 waves; Q-tile 64 (wave w owns queries w*16..w*16+15);
// K-tile 32 per iter. QK^T = split-bf16 3-pass MFMA (~fp32 scores);
// PV = single bf16 MFMA with B = V^T tile.
__global__ __launch_bounds__(256, 4) void flash_mfma(const unsigned short* __restrict__ Qh,
                                                     const unsigned short* __restrict__ Ql,
                                                     const unsigned short* __restrict__ Kh,
                                                     const unsigned short* __restrict__ Kl,
                                                     const unsigned short* __restrict__ Vt,
                                                     const float* __restrict__ kbias,
                                                     unsigned short* __restrict__ Obf) {
    constexpr int LK = 136;  // 128 + 8 pad (shorts)
    constexpr int LV = 40;   // 32 + 8 pad
    __shared__ __align__(16) unsigned short Khs[32 * LK];
    __shared__ __align__(16) unsigned short Kls[32 * LK];
    __shared__ __align__(16) unsigned short Vts[128 * LV];
    __shared__ __align__(16) unsigned short Ps[64 * LV];
    __shared__ float kb[32];

    const int t    = threadIdx.x;
    const int h    = blockIdx.y;
    const int q0   = blockIdx.x * 64;
    const int wave = t >> 6;
    const int lane = t & 63;
    const int lrow = lane & 15, quad = lane >> 4;

    // Q fragments from global, held in registers for the whole kernel.
    bf16x8 qh[4], ql[4];
    {
        const unsigned short* qb = Qh + ((size_t)h * S_LEN + q0 + wave * 16 + lrow) * HD;
        const unsigned short* qlb = Ql + ((size_t)h * S_LEN + q0 + wave * 16 + lrow) * HD;
        for (int kk = 0; kk < 4; ++kk) {
            qh[kk] = *(const bf16x8*)(qb  + kk * 32 + quad * 8);
            ql[kk] = *(const bf16x8*)(qlb + kk * 32 + quad * 8);
        }
    }

    float mrow[4], lsum[4];
    f32x4 Ofr[8];
    for (int r = 0; r < 4; ++r) { mrow[r] = -INFINITY; lsum[r] = 0.f; }
    for (int d = 0; d < 8; ++d) Ofr[d] = (f32x4){0.f, 0.f, 0.f, 0.f};

    for (int k0 = 0; k0 < S_LEN; k0 += 32) {
        {   // stage K tile (32 x 128, hi+lo) and Vt tile (128 x 32)
            int r  = t >> 3;            // 0..31
            int c0 = (t & 7) * 16;      // 0..112
            const unsigned short* khs = Kh + ((size_t)h * S_LEN + k0 + r) * HD + c0;
            const unsigned short* kls = Kl + ((size_t)h * S_LEN + k0 + r) * HD + c0;
            *(uint4*)(&Khs[r * LK + c0])     = *(const uint4*)khs;
            *(uint4*)(&Khs[r * LK + c0 + 8]) = *(const uint4*)(khs + 8);
            *(uint4*)(&Kls[r * LK + c0])     = *(const uint4*)kls;
            *(uint4*)(&Kls[r * LK + c0 + 8]) = *(const uint4*)(kls + 8);
            int r2   = t >> 1;          // 0..127
            int half = (t & 1) * 16;
            const unsigned short* vsrc = Vt + ((size_t)(h * HD + r2)) * S_LEN + k0 + half;
            *(uint4*)(&Vts[r2 * LV + half])     = *(const uint4*)vsrc;
            *(uint4*)(&Vts[r2 * LV + half + 8]) = *(const uint4*)(vsrc + 8);
            if (t < 32) kb[t] = kbias[(size_t)h * S_LEN + k0 + t];
        }
        __syncthreads();

        // QK^T: 2 n-tiles of 16 keys, 4 k-steps, 3 split passes
        f32x4 sc[2];
        sc[0] = (f32x4){0.f, 0.f, 0.f, 0.f};
        sc[1] = (f32x4){0.f, 0.f, 0.f, 0.f};
        for (int kk = 0; kk < 4; ++kk) {
            for (int nt = 0; nt < 2; ++nt) {
                int o = (nt * 16 + lrow) * LK + kk * 32 + quad * 8;
                bf16x8 khf = *(const bf16x8*)(&Khs[o]);
                bf16x8 klf = *(const bf16x8*)(&Kls[o]);
                sc[nt] = __builtin_amdgcn_mfma_f32_16x16x32_bf16(ql[kk], khf, sc[nt], 0, 0, 0);
                sc[nt] = __builtin_amdgcn_mfma_f32_16x16x32_bf16(qh[kk], klf, sc[nt], 0, 0, 0);
                sc[nt] = __builtin_amdgcn_mfma_f32_16x16x32_bf16(qh[kk], khf, sc[nt], 0, 0, 0);
            }
        }
        float kb0 = kb[lrow], kb1 = kb[16 + lrow];

        // online softmax: lane holds rows quad*4+r, cols {lrow, 16+lrow}
        for (int r = 0; r < 4; ++r) {
            float s0 = sc[0][r] + kb0;
            float s1 = sc[1][r] + kb1;
            float mx = fmaxf(s0, s1);
            mx = fmaxf(mx, __shfl_xor(mx, 1));
            mx = fmaxf(mx, __shfl_xor(mx, 2));
            mx = fmaxf(mx, __shfl_xor(mx, 4));
            mx = fmaxf(mx, __shfl_xor(mx, 8));
            float mnew  = fmaxf(mrow[r], mx);
            float alpha = __expf(mrow[r] - mnew);
            mrow[r] = mnew;
            float p0 = __expf(s0 - mnew);
            float p1 = __expf(s1 - mnew);
            float rs = p0 + p1;
            rs += __shfl_xor(rs, 1);
            rs += __shfl_xor(rs, 2);
            rs += __shfl_xor(rs, 4);
            rs += __shfl_xor(rs, 8);
            lsum[r] = lsum[r] * alpha + rs;
            for (int d = 0; d < 8; ++d) Ofr[d][r] *= alpha;
            int prow = (wave * 16 + quad * 4 + r) * LV;
            Ps[prow + lrow]      = f2bf(p0);
            Ps[prow + 16 + lrow] = f2bf(p1);
        }

        // PV: A = P (own 16 rows, k=32 keys), B = Vt (8 d-tiles)
        // Ps write->read is wave-private (rows wave*16..+15); compiler orders
        // same-array LDS dependencies via lgkmcnt.
        bf16x8 pa = *(const bf16x8*)(&Ps[(wave * 16 + lrow) * LV + quad * 8]);
        for (int dt = 0; dt < 8; ++dt) {
            bf16x8 vb = *(const bf16x8*)(&Vts[(dt * 16 + lrow) * LV + quad * 8]);
            Ofr[dt] = __builtin_amdgcn_mfma_f32_16x16x32_bf16(pa, vb, Ofr[dt], 0, 0, 0);
        }
        __syncthreads();   // protect Khs/Kls/Vts before next stage
    }

    // epilogue: rows q0 + wave*16 + quad*4 + r; col = h*128 + dt*16 + lrow
    for (int r = 0; r < 4; ++r) {
        float inv = 1.f / lsum[r];
        int row = q0 + wave * 16 + quad * 4 + r;
        unsigned short* orow = Obf + (size_t)row * HID + h * HD + lrow;
        for (int dt = 0; dt < 8; ++dt)
            orow[dt * 16] = f2bf(Ofr[dt][r] * inv);
    }
}

// ---------------- launch ----------------
extern "C" void kernel_launch(void* const* d_in, const int* in_sizes, int n_in,
                              void* d_out, int out_size, void* d_ws, size_t ws_size,
                              hipStream_t stream) {
    const float* hs   = (const float*)d_in[0];
    const float* cosb = (const float*)d_in[1];
    const float* sinb = (const float*)d_in[2];
    const float* wq   = (const float*)d_in[3];
    const float* wk   = (const float*)d_in[4];
    const float* wv   = (const float*)d_in[5];
    const float* wo   = (const float*)d_in[6];
    float* out = (float*)d_out;
    char*  ws  = (char*)d_ws;

    // ws layout (phase-lifetime aliasing, ~176 MB):
    //  [0,67.1M):   w_qk_hi|w_qk_lo (dead after gemm3) -> Qh|Ql|Kh|Kl|kbias
    //  [67.1,134.2M): qk_f32 [S][8192]
    //  [134.2M,..): hs_hi (->Obf after GEMMs) | hs_lo | w_v | w_o | Vt
    unsigned short* w_qk_hi = (unsigned short*)(ws);
    unsigned short* w_qk_lo = (unsigned short*)(ws + 33554432);
    unsigned short* Qh      = (unsigned short*)(ws);
    unsigned short* Ql      = (unsigned short*)(ws + 8388608);
    unsigned short* Kh      = (unsigned short*)(ws + 16777216);
    unsigned short* Kl      = (unsigned short*)(ws + 25165824);
    float*          kbias   = (float*)(ws + 33554432);
    float*          qk_f32  = (float*)(ws + 67108864);
    unsigned short* hs_hi   = (unsigned short*)(ws + 134217728);
    unsigned short* hs_lo   = (unsigned short*)(ws + 142606336);
    unsigned short* Obf     = (unsigned short*)(ws + 134217728);  // aliases hs_hi
    unsigned short* w_v     = (unsigned short*)(ws + 150994944);
    unsigned short* w_o     = (unsigned short*)(ws + 159383552);
    unsigned short* Vt      = (unsigned short*)(ws + 167772160);

    {
        int n4 = (S_LEN * HID) / 4;
        cast_split<<<(n4 + 255) / 256, 256, 0, stream>>>(hs, hs_hi, hs_lo, n4);
    }
    {
        int n4 = (4096 * K_HID) / 4;
        cast_split<<<(n4 + 255) / 256, 256, 0, stream>>>(wq, w_qk_hi, w_qk_lo, n4);
        cast_split<<<(n4 + 255) / 256, 256, 0, stream>>>(
            wk, w_qk_hi + (size_t)4096 * K_HID, w_qk_lo + (size_t)4096 * K_HID, n4);
    }
    {
        int n4 = (HID * K_HID) / 4;
        cast_f32_bf16<<<(n4 + 255) / 256, 256, 0, stream>>>(wv, w_v, n4);
        cast_f32_bf16<<<(n4 + 255) / 256, 256, 0, stream>>>(wo, w_o, n4);
    }

    // QK projection, bf16x3 -> fp32  [2048, 8192]
    gemm3_nt<<<dim3(64, 16), 256, 0, stream>>>(hs_hi, hs_lo, w_qk_hi, w_qk_lo,
                                               qk_f32, S_LEN, NQK, K_HID);
    // V^T projection: Vt[d][s] = sum_k wv[d][k] * hs[s][k]   [2048_d, 2048_s]
    gemm_nt<true><<<dim3(16, 16), 256, 0, stream>>>(w_v, hs_hi, Vt, HID, S_LEN, K_HID);
    // softplus / rsqrt / RoPE -> split-bf16 Q,K + fp32 key bias
    prep_qk<<<(NHEAD * S_LEN) / 4, 256, 0, stream>>>(qk_f32, cosb, sinb,
                                                     Qh, Ql, Kh, Kl, kbias);
    // flash attention (MFMA)
    flash_mfma<<<dim3(S_LEN / 64, NHEAD), 256, 0, stream>>>(Qh, Ql, Kh, Kl, Vt, kbias, Obf);
    // output projection: out = Obf @ w_o^T (fp32 out)
    gemm_nt<false><<<dim3(16, 16), 256, 0, stream>>>(Obf, w_o, out, S_LEN, HID, K_HID);
}

// Round 4
// 624.937 us; speedup vs baseline: 1.9239x; 1.1304x over previous
//
#include <hip/hip_runtime.h>
#include <stdint.h>

// ---------------- problem constants ----------------
#define S_LEN 2048
#define HID   2048
#define NHEAD 16
#define HD    128     // head dim
#define NQK   8192    // concat q,k rows of [w_q; w_k]
#define K_HID 2048

typedef __bf16 bf16x8 __attribute__((ext_vector_type(8)));
typedef float  f32x4  __attribute__((ext_vector_type(4)));

__device__ __forceinline__ unsigned short f2bf(float f) {
    union { float f; uint32_t u; } c; c.f = f;
    uint32_t u = c.u;
    return (unsigned short)((u + 0x7fffu + ((u >> 16) & 1u)) >> 16);  // RNE
}
__device__ __forceinline__ float bf2f(unsigned short b) {
    union { uint32_t u; float f; } c; c.u = ((uint32_t)b) << 16;
    return c.f;
}
__device__ __forceinline__ float softplus_f(float x) {
    return (x > 20.f) ? x : log1pf(expf(x));
}

// ---------------- cast fp32 -> bf16 (single) ----------------
__global__ __launch_bounds__(256) void cast_f32_bf16(const float* __restrict__ in,
                                                     unsigned short* __restrict__ out,
                                                     int n4) {
    int i = blockIdx.x * 256 + threadIdx.x;
    if (i < n4) {
        float4 v = ((const float4*)in)[i];
        ushort4 o;
        o.x = f2bf(v.x); o.y = f2bf(v.y); o.z = f2bf(v.z); o.w = f2bf(v.w);
        ((ushort4*)out)[i] = o;
    }
}

// ---------------- cast fp32 -> bf16 hi + lo (split) ----------------
__global__ __launch_bounds__(256) void cast_split(const float* __restrict__ in,
                                                  unsigned short* __restrict__ hi,
                                                  unsigned short* __restrict__ lo,
                                                  int n4) {
    int i = blockIdx.x * 256 + threadIdx.x;
    if (i < n4) {
        float4 v = ((const float4*)in)[i];
        ushort4 h, l;
        h.x = f2bf(v.x); l.x = f2bf(v.x - bf2f(h.x));
        h.y = f2bf(v.y); l.y = f2bf(v.y - bf2f(h.y));
        h.z = f2bf(v.z); l.z = f2bf(v.z - bf2f(h.z));
        h.w = f2bf(v.w); l.w = f2bf(v.w - bf2f(h.w));
        ((ushort4*)hi)[i] = h;
        ((ushort4*)lo)[i] = l;
    }
}

// ---------------- single-bf16 NT GEMM: C[M,N] = A[M,K] * B[N,K]^T ----------
// C/D layout: col = lane&15, row = (lane>>4)*4 + reg  (harness-verified)
template <bool OUT_BF16>
__global__ __launch_bounds__(256) void gemm_nt(const unsigned short* __restrict__ A,
                                               const unsigned short* __restrict__ B,
                                               void* __restrict__ Cv,
                                               int M, int N, int Kd) {
    constexpr int LDT = 40;
    __shared__ __align__(16) unsigned short As[128 * LDT];
    __shared__ __align__(16) unsigned short Bs[128 * LDT];
    const int t    = threadIdx.x;
    const int m0   = blockIdx.y * 128;
    const int n0   = blockIdx.x * 128;
    const int wave = t >> 6;
    const int lane = t & 63;
    const int wm   = wave >> 1, wn = wave & 1;
    const int lrow = lane & 15, quad = lane >> 4;
    const int srow = t >> 2;
    const int scol = (t & 3) * 8;

    f32x4 acc[4][4];
    for (int i = 0; i < 4; ++i)
        for (int j = 0; j < 4; ++j)
            acc[i][j] = (f32x4){0.f, 0.f, 0.f, 0.f};

    for (int k0 = 0; k0 < Kd; k0 += 32) {
        const unsigned short* Ag = A + (size_t)(m0 + srow) * Kd + k0 + scol;
        const unsigned short* Bg = B + (size_t)(n0 + srow) * Kd + k0 + scol;
        *(uint4*)(&As[srow * LDT + scol])        = *(const uint4*)Ag;
        *(uint4*)(&As[(srow + 64) * LDT + scol]) = *(const uint4*)(Ag + (size_t)64 * Kd);
        *(uint4*)(&Bs[srow * LDT + scol])        = *(const uint4*)Bg;
        *(uint4*)(&Bs[(srow + 64) * LDT + scol]) = *(const uint4*)(Bg + (size_t)64 * Kd);
        __syncthreads();

        bf16x8 af[4], bfr[4];
        for (int tm = 0; tm < 4; ++tm)
            af[tm]  = *(const bf16x8*)(&As[(wm * 64 + tm * 16 + lrow) * LDT + quad * 8]);
        for (int tn = 0; tn < 4; ++tn)
            bfr[tn] = *(const bf16x8*)(&Bs[(wn * 64 + tn * 16 + lrow) * LDT + quad * 8]);
        for (int tm = 0; tm < 4; ++tm)
            for (int tn = 0; tn < 4; ++tn)
                acc[tm][tn] = __builtin_amdgcn_mfma_f32_16x16x32_bf16(af[tm], bfr[tn], acc[tm][tn], 0, 0, 0);
        __syncthreads();
    }

    for (int tm = 0; tm < 4; ++tm)
        for (int tn = 0; tn < 4; ++tn) {
            int col = n0 + wn * 64 + tn * 16 + lrow;
            for (int r = 0; r < 4; ++r) {
                int row = m0 + wm * 64 + tm * 16 + quad * 4 + r;
                if (OUT_BF16)
                    ((unsigned short*)Cv)[(size_t)row * N + col] = f2bf(acc[tm][tn][r]);
                else
                    ((float*)Cv)[(size_t)row * N + col] = acc[tm][tn][r];
            }
        }
}

// ---------------- bf16x3 split NT GEMM (~fp32 precision), fp32 out ---------
__global__ __launch_bounds__(256) void gemm3_nt(const unsigned short* __restrict__ Ah,
                                                const unsigned short* __restrict__ Al,
                                                const unsigned short* __restrict__ Bh,
                                                const unsigned short* __restrict__ Bl,
                                                float* __restrict__ C,
                                                int M, int N, int Kd) {
    constexpr int LDT = 40;
    __shared__ __align__(16) unsigned short Ash[128 * LDT];
    __shared__ __align__(16) unsigned short Asl[128 * LDT];
    __shared__ __align__(16) unsigned short Bsh[128 * LDT];
    __shared__ __align__(16) unsigned short Bsl[128 * LDT];
    const int t    = threadIdx.x;
    const int m0   = blockIdx.y * 128;
    const int n0   = blockIdx.x * 128;
    const int wave = t >> 6;
    const int lane = t & 63;
    const int wm   = wave >> 1, wn = wave & 1;
    const int lrow = lane & 15, quad = lane >> 4;
    const int srow = t >> 2;
    const int scol = (t & 3) * 8;

    f32x4 acc[4][4];
    for (int i = 0; i < 4; ++i)
        for (int j = 0; j < 4; ++j)
            acc[i][j] = (f32x4){0.f, 0.f, 0.f, 0.f};

    for (int k0 = 0; k0 < Kd; k0 += 32) {
        size_t offA0 = (size_t)(m0 + srow) * Kd + k0 + scol;
        size_t offA1 = offA0 + (size_t)64 * Kd;
        size_t offB0 = (size_t)(n0 + srow) * Kd + k0 + scol;
        size_t offB1 = offB0 + (size_t)64 * Kd;
        *(uint4*)(&Ash[srow * LDT + scol])        = *(const uint4*)(Ah + offA0);
        *(uint4*)(&Ash[(srow + 64) * LDT + scol]) = *(const uint4*)(Ah + offA1);
        *(uint4*)(&Asl[srow * LDT + scol])        = *(const uint4*)(Al + offA0);
        *(uint4*)(&Asl[(srow + 64) * LDT + scol]) = *(const uint4*)(Al + offA1);
        *(uint4*)(&Bsh[srow * LDT + scol])        = *(const uint4*)(Bh + offB0);
        *(uint4*)(&Bsh[(srow + 64) * LDT + scol]) = *(const uint4*)(Bh + offB1);
        *(uint4*)(&Bsl[srow * LDT + scol])        = *(const uint4*)(Bl + offB0);
        *(uint4*)(&Bsl[(srow + 64) * LDT + scol]) = *(const uint4*)(Bl + offB1);
        __syncthreads();

        bf16x8 afh[4], afl[4], bfh[4], bfl[4];
        for (int tm = 0; tm < 4; ++tm) {
            int o = (wm * 64 + tm * 16 + lrow) * LDT + quad * 8;
            afh[tm] = *(const bf16x8*)(&Ash[o]);
            afl[tm] = *(const bf16x8*)(&Asl[o]);
        }
        for (int tn = 0; tn < 4; ++tn) {
            int o = (wn * 64 + tn * 16 + lrow) * LDT + quad * 8;
            bfh[tn] = *(const bf16x8*)(&Bsh[o]);
            bfl[tn] = *(const bf16x8*)(&Bsl[o]);
        }
        for (int tm = 0; tm < 4; ++tm)
            for (int tn = 0; tn < 4; ++tn) {
                acc[tm][tn] = __builtin_amdgcn_mfma_f32_16x16x32_bf16(afl[tm], bfh[tn], acc[tm][tn], 0, 0, 0);
                acc[tm][tn] = __builtin_amdgcn_mfma_f32_16x16x32_bf16(afh[tm], bfl[tn], acc[tm][tn], 0, 0, 0);
                acc[tm][tn] = __builtin_amdgcn_mfma_f32_16x16x32_bf16(afh[tm], bfh[tn], acc[tm][tn], 0, 0, 0);
            }
        __syncthreads();
    }

    for (int tm = 0; tm < 4; ++tm)
        for (int tn = 0; tn < 4; ++tn) {
            int col = n0 + wn * 64 + tn * 16 + lrow;
            for (int r = 0; r < 4; ++r) {
                int row = m0 + wm * 64 + tm * 16 + quad * 4 + r;
                C[(size_t)row * N + col] = acc[tm][tn][r];
            }
        }
}

// ---------------- prep: softplus + rsqrt + RoPE; emits split-bf16 Q/K ------
__global__ __launch_bounds__(256) void prep_qk(const float* __restrict__ qk,
                                               const float* __restrict__ cosb,
                                               const float* __restrict__ sinb,
                                               unsigned short* __restrict__ Qh,
                                               unsigned short* __restrict__ Ql,
                                               unsigned short* __restrict__ Kh,
                                               unsigned short* __restrict__ Kl,
                                               float* __restrict__ kbias) {
    int gid  = blockIdx.x * 4 + (threadIdx.x >> 6);
    int lane = threadIdx.x & 63;
    int h = gid >> 11;
    int s = gid & 2047;
    int d1 = lane, d2 = lane + 64;
    const float* row = qk + (size_t)s * NQK;
    float c1 = cosb[s * HD + d1], c2 = cosb[s * HD + d2];
    float s1 = sinb[s * HD + d1], s2 = sinb[s * HD + d2];
    size_t ob = ((size_t)h * S_LEN + s) * HD;

    {   // Q side (row constants cancel in softmax)
        int base = h * 256;
        float mu1 = row[base + d1],            mu2 = row[base + d2];
        float sg1 = softplus_f(row[base + 128 + d1]) + 1e-4f;
        float sg2 = softplus_f(row[base + 128 + d2]) + 1e-4f;
        float w1 = mu1 * rsqrtf(sg1), w2 = mu2 * rsqrtf(sg2);
        float o1 = w1 * c1 - w2 * s1;
        float o2 = w2 * c2 + w1 * s2;
        unsigned short h1 = f2bf(o1), h2 = f2bf(o2);
        Qh[ob + d1] = h1; Ql[ob + d1] = f2bf(o1 - bf2f(h1));
        Qh[ob + d2] = h2; Ql[ob + d2] = f2bf(o2 - bf2f(h2));
    }
    {   // K side + bias = -0.5*(|kw|^2 + sum log sigma)
        int base = 4096 + h * 256;
        float mu1 = row[base + d1],            mu2 = row[base + d2];
        float sg1 = softplus_f(row[base + 128 + d1]) + 1e-4f;
        float sg2 = softplus_f(row[base + 128 + d2]) + 1e-4f;
        float w1 = mu1 * rsqrtf(sg1), w2 = mu2 * rsqrtf(sg2);
        float o1 = w1 * c1 - w2 * s1;
        float o2 = w2 * c2 + w1 * s2;
        unsigned short h1 = f2bf(o1), h2 = f2bf(o2);
        Kh[ob + d1] = h1; Kl[ob + d1] = f2bf(o1 - bf2f(h1));
        Kh[ob + d2] = h2; Kl[ob + d2] = f2bf(o2 - bf2f(h2));
        float part = o1 * o1 + o2 * o2 + logf(sg1) + logf(sg2);
        for (int off = 32; off > 0; off >>= 1) part += __shfl_down(part, off);
        if (lane == 0) kbias[(size_t)h * S_LEN + s] = -0.5f * part;
    }
}

// ---------------- flash attention, MFMA, key-split partials ----------------
// Block 256 thr = 4 waves; Q-tile 128 (wave w owns 32 queries = 2 m-frags);
// K-tile 64/iter; blockIdx.z = key-half (1024 keys each).
// Emits UNNORMALIZED O (fp32) + per-row (m, l) -> merged by flash_merge.
__global__ __launch_bounds__(256, 2) void flash_mfma(const unsigned short* __restrict__ Qh,
                                                     const unsigned short* __restrict__ Ql,
                                                     const unsigned short* __restrict__ Kh,
                                                     const unsigned short* __restrict__ Kl,
                                                     const unsigned short* __restrict__ Vt,
                                                     const float* __restrict__ kbias,
                                                     float* __restrict__ OP,
                                                     float* __restrict__ ML) {
    constexpr int LK = 136;  // 128 + 8 pad (shorts)
    constexpr int LV = 72;   // 64 + 8 pad
    __shared__ __align__(16) unsigned short Khs[64 * LK];
    __shared__ __align__(16) unsigned short Kls[64 * LK];
    __shared__ __align__(16) unsigned short Vts[128 * LV];
    __shared__ __align__(16) unsigned short Ps[128 * LV];
    __shared__ float kb[64];

    const int t    = threadIdx.x;
    const int h    = blockIdx.y;
    const int q0   = blockIdx.x * 128;
    const int kz   = blockIdx.z;
    const int wave = t >> 6;
    const int lane = t & 63;
    const int lrow = lane & 15, quad = lane >> 4;

    // Q fragments (2 m-tiles x 4 k-steps, hi+lo), held in registers.
    bf16x8 qh[2][4], ql[2][4];
    for (int m = 0; m < 2; ++m) {
        size_t rb = ((size_t)h * S_LEN + q0 + wave * 32 + m * 16 + lrow) * HD;
        for (int kk = 0; kk < 4; ++kk) {
            qh[m][kk] = *(const bf16x8*)(Qh + rb + kk * 32 + quad * 8);
            ql[m][kk] = *(const bf16x8*)(Ql + rb + kk * 32 + quad * 8);
        }
    }

    float mrow[2][4], lsum[2][4];
    f32x4 Ofr[2][8];
    for (int m = 0; m < 2; ++m)
        for (int r = 0; r < 4; ++r) { mrow[m][r] = -INFINITY; lsum[m][r] = 0.f; }
    for (int m = 0; m < 2; ++m)
        for (int d = 0; d < 8; ++d) Ofr[m][d] = (f32x4){0.f, 0.f, 0.f, 0.f};

    const int kbeg = kz * 1024;
    for (int k0 = kbeg; k0 < kbeg + 1024; k0 += 64) {
        {   // stage K (64 x 128, hi+lo) and Vt (128 x 64)
            int r  = t >> 2;            // 0..63
            int cb = (t & 3) * 32;      // 0,32,64,96
            const unsigned short* khp = Kh + ((size_t)h * S_LEN + k0 + r) * HD + cb;
            const unsigned short* klp = Kl + ((size_t)h * S_LEN + k0 + r) * HD + cb;
            for (int i = 0; i < 4; ++i) {
                *(uint4*)(&Khs[r * LK + cb + i * 8]) = *(const uint4*)(khp + i * 8);
                *(uint4*)(&Kls[r * LK + cb + i * 8]) = *(const uint4*)(klp + i * 8);
            }
            int r2  = t >> 1;           // 0..127
            int cb2 = (t & 1) * 32;     // 0,32
            const unsigned short* vp = Vt + ((size_t)(h * HD + r2)) * S_LEN + k0 + cb2;
            for (int i = 0; i < 4; ++i)
                *(uint4*)(&Vts[r2 * LV + cb2 + i * 8]) = *(const uint4*)(vp + i * 8);
            if (t < 64) kb[t] = kbias[(size_t)h * S_LEN + k0 + t];
        }
        __syncthreads();

        // QK^T: 4 n-tiles (64 keys), 4 k-steps, 3 split passes, 2 m-tiles
        f32x4 sc[2][4];
        for (int m = 0; m < 2; ++m)
            for (int nt = 0; nt < 4; ++nt) sc[m][nt] = (f32x4){0.f, 0.f, 0.f, 0.f};
        for (int kk = 0; kk < 4; ++kk)
            for (int nt = 0; nt < 4; ++nt) {
                int o = (nt * 16 + lrow) * LK + kk * 32 + quad * 8;
                bf16x8 khf = *(const bf16x8*)(&Khs[o]);
                bf16x8 klf = *(const bf16x8*)(&Kls[o]);
                for (int m = 0; m < 2; ++m) {
                    sc[m][nt] = __builtin_amdgcn_mfma_f32_16x16x32_bf16(ql[m][kk], khf, sc[m][nt], 0, 0, 0);
                    sc[m][nt] = __builtin_amdgcn_mfma_f32_16x16x32_bf16(qh[m][kk], klf, sc[m][nt], 0, 0, 0);
                    sc[m][nt] = __builtin_amdgcn_mfma_f32_16x16x32_bf16(qh[m][kk], khf, sc[m][nt], 0, 0, 0);
                }
            }
        float kbn[4] = {kb[lrow], kb[16 + lrow], kb[32 + lrow], kb[48 + lrow]};

        // online softmax per (m, r); lane's 16 lrow columns cover 64 keys
        for (int m = 0; m < 2; ++m)
            for (int r = 0; r < 4; ++r) {
                float s0 = sc[m][0][r] + kbn[0];
                float s1 = sc[m][1][r] + kbn[1];
                float s2 = sc[m][2][r] + kbn[2];
                float s3 = sc[m][3][r] + kbn[3];
                float mx = fmaxf(fmaxf(s0, s1), fmaxf(s2, s3));
                mx = fmaxf(mx, __shfl_xor(mx, 1));
                mx = fmaxf(mx, __shfl_xor(mx, 2));
                mx = fmaxf(mx, __shfl_xor(mx, 4));
                mx = fmaxf(mx, __shfl_xor(mx, 8));
                float mnew  = fmaxf(mrow[m][r], mx);
                float alpha = __expf(mrow[m][r] - mnew);
                mrow[m][r] = mnew;
                float p0 = __expf(s0 - mnew);
                float p1 = __expf(s1 - mnew);
                float p2 = __expf(s2 - mnew);
                float p3 = __expf(s3 - mnew);
                float rs = (p0 + p1) + (p2 + p3);
                rs += __shfl_xor(rs, 1);
                rs += __shfl_xor(rs, 2);
                rs += __shfl_xor(rs, 4);
                rs += __shfl_xor(rs, 8);
                lsum[m][r] = lsum[m][r] * alpha + rs;
                for (int d = 0; d < 8; ++d) Ofr[m][d][r] *= alpha;
                int prow = (wave * 32 + m * 16 + quad * 4 + r) * LV;
                Ps[prow + lrow]      = f2bf(p0);
                Ps[prow + 16 + lrow] = f2bf(p1);
                Ps[prow + 32 + lrow] = f2bf(p2);
                Ps[prow + 48 + lrow] = f2bf(p3);
            }

        // PV: A = P (wave-private rows), B = Vt; 2 key-chunks x 8 d-tiles
        for (int c = 0; c < 2; ++c) {
            bf16x8 pa0 = *(const bf16x8*)(&Ps[(wave * 32 + lrow) * LV + c * 32 + quad * 8]);
            bf16x8 pa1 = *(const bf16x8*)(&Ps[(wave * 32 + 16 + lrow) * LV + c * 32 + quad * 8]);
            for (int dt = 0; dt < 8; ++dt) {
                bf16x8 vb = *(const bf16x8*)(&Vts[(dt * 16 + lrow) * LV + c * 32 + quad * 8]);
                Ofr[0][dt] = __builtin_amdgcn_mfma_f32_16x16x32_bf16(pa0, vb, Ofr[0][dt], 0, 0, 0);
                Ofr[1][dt] = __builtin_amdgcn_mfma_f32_16x16x32_bf16(pa1, vb, Ofr[1][dt], 0, 0, 0);
            }
        }
        __syncthreads();
    }

    // epilogue: unnormalized O + (m,l) partials for this key-half
    size_t obase = (size_t)(kz * NHEAD + h) * S_LEN;
    for (int m = 0; m < 2; ++m)
        for (int r = 0; r < 4; ++r) {
            int qrow = q0 + wave * 32 + m * 16 + quad * 4 + r;
            float* op = OP + (obase + qrow) * HD;
            for (int dt = 0; dt < 8; ++dt)
                op[dt * 16 + lrow] = Ofr[m][dt][r];
            if (lrow == 0) {
                ML[(obase + qrow) * 2]     = mrow[m][r];
                ML[(obase + qrow) * 2 + 1] = lsum[m][r];
            }
        }
}

// ---------------- merge the two key-halves (log-sum-exp) -> bf16 Obf -------
__global__ __launch_bounds__(256) void flash_merge(const float* __restrict__ OP,
                                                   const float* __restrict__ ML,
                                                   unsigned short* __restrict__ Obf) {
    int row = blockIdx.x * 2 + (threadIdx.x >> 7);   // 0..32767 = h*2048+q
    int d   = threadIdx.x & 127;
    int h = row >> 11, q = row & 2047;
    size_t i0 = (size_t)h * S_LEN + q;
    size_t i1 = (size_t)(NHEAD + h) * S_LEN + q;
    float m0 = ML[i0 * 2], l0 = ML[i0 * 2 + 1];
    float m1 = ML[i1 * 2], l1 = ML[i1 * 2 + 1];
    float mf = fmaxf(m0, m1);
    float w0 = __expf(m0 - mf), w1 = __expf(m1 - mf);
    float inv = 1.f / (l0 * w0 + l1 * w1);
    float o = (OP[i0 * HD + d] * w0 + OP[i1 * HD + d] * w1) * inv;
    Obf[(size_t)q * HID + h * HD + d] = f2bf(o);
}

// ---------------- launch ----------------
extern "C" void kernel_launch(void* const* d_in, const int* in_sizes, int n_in,
                              void* d_out, int out_size, void* d_ws, size_t ws_size,
                              hipStream_t stream) {
    const float* hs   = (const float*)d_in[0];
    const float* cosb = (const float*)d_in[1];
    const float* sinb = (const float*)d_in[2];
    const float* wq   = (const float*)d_in[3];
    const float* wk   = (const float*)d_in[4];
    const float* wv   = (const float*)d_in[5];
    const float* wo   = (const float*)d_in[6];
    float* out = (float*)d_out;
    char*  ws  = (char*)d_ws;

    // ws layout (phase-lifetime aliasing, ~176 MB):
    //  [0,33.6M):      w_qk_hi (dead after gemm3) -> Qh|Ql|Kh|Kl
    //  [33.6,67.1M):   w_qk_lo (dead after gemm3) -> kbias
    //  [67.1,134.2M):  qk_f32 (dead after prep)   -> OP (33.6M) | ML (1M)
    //  [134.2M,..):    hs_hi (->Obf after GEMMs) | hs_lo | w_v | w_o | Vt
    unsigned short* w_qk_hi = (unsigned short*)(ws);
    unsigned short* w_qk_lo = (unsigned short*)(ws + 33554432);
    unsigned short* Qh      = (unsigned short*)(ws);
    unsigned short* Ql      = (unsigned short*)(ws + 8388608);
    unsigned short* Kh      = (unsigned short*)(ws + 16777216);
    unsigned short* Kl      = (unsigned short*)(ws + 25165824);
    float*          kbias   = (float*)(ws + 33554432);
    float*          qk_f32  = (float*)(ws + 67108864);
    float*          OP      = (float*)(ws + 67108864);            // aliases qk_f32
    float*          ML      = (float*)(ws + 67108864 + 33554432);
    unsigned short* hs_hi   = (unsigned short*)(ws + 134217728);
    unsigned short* hs_lo   = (unsigned short*)(ws + 142606336);
    unsigned short* Obf     = (unsigned short*)(ws + 134217728);  // aliases hs_hi
    unsigned short* w_v     = (unsigned short*)(ws + 150994944);
    unsigned short* w_o     = (unsigned short*)(ws + 159383552);
    unsigned short* Vt      = (unsigned short*)(ws + 167772160);

    {
        int n4 = (S_LEN * HID) / 4;
        cast_split<<<(n4 + 255) / 256, 256, 0, stream>>>(hs, hs_hi, hs_lo, n4);
    }
    {
        int n4 = (4096 * K_HID) / 4;
        cast_split<<<(n4 + 255) / 256, 256, 0, stream>>>(wq, w_qk_hi, w_qk_lo, n4);
        cast_split<<<(n4 + 255) / 256, 256, 0, stream>>>(
            wk, w_qk_hi + (size_t)4096 * K_HID, w_qk_lo + (size_t)4096 * K_HID, n4);
    }
    {
        int n4 = (HID * K_HID) / 4;
        cast_f32_bf16<<<(n4 + 255) / 256, 256, 0, stream>>>(wv, w_v, n4);
        cast_f32_bf16<<<(n4 + 255) / 256, 256, 0, stream>>>(wo, w_o, n4);
    }

    // QK projection, bf16x3 -> fp32  [2048, 8192]
    gemm3_nt<<<dim3(64, 16), 256, 0, stream>>>(hs_hi, hs_lo, w_qk_hi, w_qk_lo,
                                               qk_f32, S_LEN, NQK, K_HID);
    // V^T projection: Vt[d][s] = sum_k wv[d][k] * hs[s][k]
    gemm_nt<true><<<dim3(16, 16), 256, 0, stream>>>(w_v, hs_hi, Vt, HID, S_LEN, K_HID);
    // softplus / rsqrt / RoPE -> split-bf16 Q,K + fp32 key bias
    prep_qk<<<(NHEAD * S_LEN) / 4, 256, 0, stream>>>(qk_f32, cosb, sinb,
                                                     Qh, Ql, Kh, Kl, kbias);
    // flash attention (MFMA, key-split 2) -> partials (overwrites dead qk_f32)
    flash_mfma<<<dim3(S_LEN / 128, NHEAD, 2), 256, 0, stream>>>(Qh, Ql, Kh, Kl, Vt,
                                                                kbias, OP, ML);
    // merge halves -> bf16 attn_out
    flash_merge<<<(NHEAD * S_LEN) / 2, 256, 0, stream>>>(OP, ML, Obf);
    // output projection: out = Obf @ w_o^T (fp32 out)
    gemm_nt<false><<<dim3(16, 16), 256, 0, stream>>>(Obf, w_o, out, S_LEN, HID, K_HID);
}

// Round 5
// 484.547 us; speedup vs baseline: 2.4814x; 1.2897x over previous
//
#include <hip/hip_runtime.h>
#include <stdint.h>

// ---------------- problem constants ----------------
#define S_LEN 2048
#define HID   2048
#define NHEAD 16
#define HD    128     // head dim
#define NQK   8192    // concat q,k rows of [w_q; w_k]
#define K_HID 2048

typedef _Float16 f16x8 __attribute__((ext_vector_type(8)));
typedef float    f32x4 __attribute__((ext_vector_type(4)));

__device__ __forceinline__ unsigned short f2h(float f) {
    _Float16 h = (_Float16)f;                    // RNE
    union { _Float16 h; unsigned short u; } c; c.h = h;
    return c.u;
}
__device__ __forceinline__ float h2f(unsigned short b) {
    union { unsigned short u; _Float16 h; } c; c.u = b;
    return (float)c.h;
}
__device__ __forceinline__ float softplus_f(float x) {
    return (x > 20.f) ? x : log1pf(expf(x));
}

// ---------------- cast fp32 -> fp16 ----------------
__global__ __launch_bounds__(256) void cast_f16(const float* __restrict__ in,
                                                unsigned short* __restrict__ out,
                                                int n4) {
    int i = blockIdx.x * 256 + threadIdx.x;
    if (i < n4) {
        float4 v = ((const float4*)in)[i];
        ushort4 o;
        o.x = f2h(v.x); o.y = f2h(v.y); o.z = f2h(v.z); o.w = f2h(v.w);
        ((ushort4*)out)[i] = o;
    }
}

// ---------------- fp16 NT GEMM: C[M,N] = A[M,K] * B[N,K]^T -----------------
// 128x128 tile, BK=32, 256 thr = 4 waves (2x2), 4x4 MFMA tiles/wave.
// C/D layout: col = lane&15, row = (lane>>4)*4 + reg  (harness-verified)
template <bool OUT_F16>
__global__ __launch_bounds__(256) void gemm_nt_f16(const unsigned short* __restrict__ A,
                                                   const unsigned short* __restrict__ B,
                                                   void* __restrict__ Cv,
                                                   int M, int N, int Kd) {
    constexpr int LDT = 40;  // 32 + 8 pad
    __shared__ __align__(16) unsigned short As[128 * LDT];
    __shared__ __align__(16) unsigned short Bs[128 * LDT];
    const int t    = threadIdx.x;
    const int m0   = blockIdx.y * 128;
    const int n0   = blockIdx.x * 128;
    const int wave = t >> 6;
    const int lane = t & 63;
    const int wm   = wave >> 1, wn = wave & 1;
    const int lrow = lane & 15, quad = lane >> 4;
    const int srow = t >> 2;
    const int scol = (t & 3) * 8;

    f32x4 acc[4][4];
    for (int i = 0; i < 4; ++i)
        for (int j = 0; j < 4; ++j)
            acc[i][j] = (f32x4){0.f, 0.f, 0.f, 0.f};

    for (int k0 = 0; k0 < Kd; k0 += 32) {
        const unsigned short* Ag = A + (size_t)(m0 + srow) * Kd + k0 + scol;
        const unsigned short* Bg = B + (size_t)(n0 + srow) * Kd + k0 + scol;
        *(uint4*)(&As[srow * LDT + scol])        = *(const uint4*)Ag;
        *(uint4*)(&As[(srow + 64) * LDT + scol]) = *(const uint4*)(Ag + (size_t)64 * Kd);
        *(uint4*)(&Bs[srow * LDT + scol])        = *(const uint4*)Bg;
        *(uint4*)(&Bs[(srow + 64) * LDT + scol]) = *(const uint4*)(Bg + (size_t)64 * Kd);
        __syncthreads();

        f16x8 af[4], bfr[4];
        for (int tm = 0; tm < 4; ++tm)
            af[tm]  = *(const f16x8*)(&As[(wm * 64 + tm * 16 + lrow) * LDT + quad * 8]);
        for (int tn = 0; tn < 4; ++tn)
            bfr[tn] = *(const f16x8*)(&Bs[(wn * 64 + tn * 16 + lrow) * LDT + quad * 8]);
        for (int tm = 0; tm < 4; ++tm)
            for (int tn = 0; tn < 4; ++tn)
                acc[tm][tn] = __builtin_amdgcn_mfma_f32_16x16x32_f16(af[tm], bfr[tn], acc[tm][tn], 0, 0, 0);
        __syncthreads();
    }

    for (int tm = 0; tm < 4; ++tm)
        for (int tn = 0; tn < 4; ++tn) {
            int col = n0 + wn * 64 + tn * 16 + lrow;
            for (int r = 0; r < 4; ++r) {
                int row = m0 + wm * 64 + tm * 16 + quad * 4 + r;
                if (OUT_F16)
                    ((unsigned short*)Cv)[(size_t)row * N + col] = f2h(acc[tm][tn][r]);
                else
                    ((float*)Cv)[(size_t)row * N + col] = acc[tm][tn][r];
            }
        }
}

// ---------------- prep: softplus + rsqrt + RoPE -> fp16 q̂,k̂ ---------------
// CONSISTENCY: kbias is computed from the fp16-ROUNDED k̂ so that
// score = q̂·k̂ - 0.5(|k̂|² + logdet) is the exact score of the perturbed
// problem (q-side constants cancel in softmax exactly).
__global__ __launch_bounds__(256) void prep_qk(const float* __restrict__ qk,
                                               const float* __restrict__ cosb,
                                               const float* __restrict__ sinb,
                                               unsigned short* __restrict__ Q16,
                                               unsigned short* __restrict__ K16,
                                               float* __restrict__ kbias) {
    int gid  = blockIdx.x * 4 + (threadIdx.x >> 6);
    int lane = threadIdx.x & 63;
    int h = gid >> 11;
    int s = gid & 2047;
    int d1 = lane, d2 = lane + 64;
    const float* row = qk + (size_t)s * NQK;
    float c1 = cosb[s * HD + d1], c2 = cosb[s * HD + d2];
    float s1 = sinb[s * HD + d1], s2 = sinb[s * HD + d2];
    size_t ob = ((size_t)h * S_LEN + s) * HD;

    {   // Q side
        int base = h * 256;
        float mu1 = row[base + d1],            mu2 = row[base + d2];
        float sg1 = softplus_f(row[base + 128 + d1]) + 1e-4f;
        float sg2 = softplus_f(row[base + 128 + d2]) + 1e-4f;
        float w1 = mu1 * rsqrtf(sg1), w2 = mu2 * rsqrtf(sg2);
        float o1 = w1 * c1 - w2 * s1;
        float o2 = w2 * c2 + w1 * s2;
        Q16[ob + d1] = f2h(o1);
        Q16[ob + d2] = f2h(o2);
    }
    {   // K side + bias from ROUNDED k̂
        int base = 4096 + h * 256;
        float mu1 = row[base + d1],            mu2 = row[base + d2];
        float sg1 = softplus_f(row[base + 128 + d1]) + 1e-4f;
        float sg2 = softplus_f(row[base + 128 + d2]) + 1e-4f;
        float w1 = mu1 * rsqrtf(sg1), w2 = mu2 * rsqrtf(sg2);
        float o1 = w1 * c1 - w2 * s1;
        float o2 = w2 * c2 + w1 * s2;
        unsigned short k1 = f2h(o1), k2 = f2h(o2);
        K16[ob + d1] = k1; K16[ob + d2] = k2;
        float r1 = h2f(k1), r2 = h2f(k2);
        float part = r1 * r1 + r2 * r2 + logf(sg1) + logf(sg2);
        for (int off = 32; off > 0; off >>= 1) part += __shfl_down(part, off);
        if (lane == 0) kbias[(size_t)h * S_LEN + s] = -0.5f * part;
    }
}

// ---------------- flash attention, fp16 MFMA, key-split partials -----------
// Block 256 thr = 4 waves; Q-tile 128 (wave owns 32 queries = 2 m-frags);
// K-tile 64/iter; blockIdx.z = key-half (1024 keys each).
// Emits UNNORMALIZED O (fp32) + per-row (m, l) -> merged by flash_merge.
__global__ __launch_bounds__(256, 2) void flash_mfma(const unsigned short* __restrict__ Q16,
                                                     const unsigned short* __restrict__ K16,
                                                     const unsigned short* __restrict__ Vt,
                                                     const float* __restrict__ kbias,
                                                     float* __restrict__ OP,
                                                     float* __restrict__ ML) {
    constexpr int LK = 136;  // 128 + 8 pad (halves)
    constexpr int LV = 72;   // 64 + 8 pad
    __shared__ __align__(16) unsigned short Khs[64 * LK];
    __shared__ __align__(16) unsigned short Vts[128 * LV];
    __shared__ __align__(16) unsigned short Ps[128 * LV];
    __shared__ float kb[64];

    const int t    = threadIdx.x;
    const int h    = blockIdx.y;
    const int q0   = blockIdx.x * 128;
    const int kz   = blockIdx.z;
    const int wave = t >> 6;
    const int lane = t & 63;
    const int lrow = lane & 15, quad = lane >> 4;

    // Q fragments (2 m-tiles x 4 k-steps), registers for the whole kernel.
    f16x8 qf[2][4];
    for (int m = 0; m < 2; ++m) {
        size_t rb = ((size_t)h * S_LEN + q0 + wave * 32 + m * 16 + lrow) * HD;
        for (int kk = 0; kk < 4; ++kk)
            qf[m][kk] = *(const f16x8*)(Q16 + rb + kk * 32 + quad * 8);
    }

    float mrow[2][4], lsum[2][4];
    f32x4 Ofr[2][8];
    for (int m = 0; m < 2; ++m)
        for (int r = 0; r < 4; ++r) { mrow[m][r] = -INFINITY; lsum[m][r] = 0.f; }
    for (int m = 0; m < 2; ++m)
        for (int d = 0; d < 8; ++d) Ofr[m][d] = (f32x4){0.f, 0.f, 0.f, 0.f};

    const int kbeg = kz * 1024;
    for (int k0 = kbeg; k0 < kbeg + 1024; k0 += 64) {
        {   // stage K (64 x 128) and Vt (128 x 64)
            int r  = t >> 2;            // 0..63
            int cb = (t & 3) * 32;      // 0,32,64,96
            const unsigned short* kp = K16 + ((size_t)h * S_LEN + k0 + r) * HD + cb;
            for (int i = 0; i < 4; ++i)
                *(uint4*)(&Khs[r * LK + cb + i * 8]) = *(const uint4*)(kp + i * 8);
            int r2  = t >> 1;           // 0..127
            int cb2 = (t & 1) * 32;     // 0,32
            const unsigned short* vp = Vt + ((size_t)(h * HD + r2)) * S_LEN + k0 + cb2;
            for (int i = 0; i < 4; ++i)
                *(uint4*)(&Vts[r2 * LV + cb2 + i * 8]) = *(const uint4*)(vp + i * 8);
            if (t < 64) kb[t] = kbias[(size_t)h * S_LEN + k0 + t];
        }
        __syncthreads();

        // QK^T: 4 n-tiles (64 keys) x 4 k-steps x 2 m-tiles, single fp16 pass
        f32x4 sc[2][4];
        for (int m = 0; m < 2; ++m)
            for (int nt = 0; nt < 4; ++nt) sc[m][nt] = (f32x4){0.f, 0.f, 0.f, 0.f};
        for (int kk = 0; kk < 4; ++kk)
            for (int nt = 0; nt < 4; ++nt) {
                f16x8 khf = *(const f16x8*)(&Khs[(nt * 16 + lrow) * LK + kk * 32 + quad * 8]);
                sc[0][nt] = __builtin_amdgcn_mfma_f32_16x16x32_f16(qf[0][kk], khf, sc[0][nt], 0, 0, 0);
                sc[1][nt] = __builtin_amdgcn_mfma_f32_16x16x32_f16(qf[1][kk], khf, sc[1][nt], 0, 0, 0);
            }
        float kbn[4] = {kb[lrow], kb[16 + lrow], kb[32 + lrow], kb[48 + lrow]};

        // online softmax per (m, r)
        for (int m = 0; m < 2; ++m)
            for (int r = 0; r < 4; ++r) {
                float s0 = sc[m][0][r] + kbn[0];
                float s1 = sc[m][1][r] + kbn[1];
                float s2 = sc[m][2][r] + kbn[2];
                float s3 = sc[m][3][r] + kbn[3];
                float mx = fmaxf(fmaxf(s0, s1), fmaxf(s2, s3));
                mx = fmaxf(mx, __shfl_xor(mx, 1));
                mx = fmaxf(mx, __shfl_xor(mx, 2));
                mx = fmaxf(mx, __shfl_xor(mx, 4));
                mx = fmaxf(mx, __shfl_xor(mx, 8));
                float mnew  = fmaxf(mrow[m][r], mx);
                float alpha = __expf(mrow[m][r] - mnew);
                mrow[m][r] = mnew;
                float p0 = __expf(s0 - mnew);
                float p1 = __expf(s1 - mnew);
                float p2 = __expf(s2 - mnew);
                float p3 = __expf(s3 - mnew);
                float rs = (p0 + p1) + (p2 + p3);
                rs += __shfl_xor(rs, 1);
                rs += __shfl_xor(rs, 2);
                rs += __shfl_xor(rs, 4);
                rs += __shfl_xor(rs, 8);
                lsum[m][r] = lsum[m][r] * alpha + rs;
                for (int d = 0; d < 8; ++d) Ofr[m][d][r] *= alpha;
                int prow = (wave * 32 + m * 16 + quad * 4 + r) * LV;
                Ps[prow + lrow]      = f2h(p0);
                Ps[prow + 16 + lrow] = f2h(p1);
                Ps[prow + 32 + lrow] = f2h(p2);
                Ps[prow + 48 + lrow] = f2h(p3);
            }

        // PV: A = P (wave-private rows), B = Vt; 2 key-chunks x 8 d-tiles
        for (int c = 0; c < 2; ++c) {
            f16x8 pa0 = *(const f16x8*)(&Ps[(wave * 32 + lrow) * LV + c * 32 + quad * 8]);
            f16x8 pa1 = *(const f16x8*)(&Ps[(wave * 32 + 16 + lrow) * LV + c * 32 + quad * 8]);
            for (int dt = 0; dt < 8; ++dt) {
                f16x8 vb = *(const f16x8*)(&Vts[(dt * 16 + lrow) * LV + c * 32 + quad * 8]);
                Ofr[0][dt] = __builtin_amdgcn_mfma_f32_16x16x32_f16(pa0, vb, Ofr[0][dt], 0, 0, 0);
                Ofr[1][dt] = __builtin_amdgcn_mfma_f32_16x16x32_f16(pa1, vb, Ofr[1][dt], 0, 0, 0);
            }
        }
        __syncthreads();
    }

    // epilogue: unnormalized O + (m,l) partials for this key-half
    size_t obase = (size_t)(kz * NHEAD + h) * S_LEN;
    for (int m = 0; m < 2; ++m)
        for (int r = 0; r < 4; ++r) {
            int qrow = q0 + wave * 32 + m * 16 + quad * 4 + r;
            float* op = OP + (obase + qrow) * HD;
            for (int dt = 0; dt < 8; ++dt)
                op[dt * 16 + lrow] = Ofr[m][dt][r];
            if (lrow == 0) {
                ML[(obase + qrow) * 2]     = mrow[m][r];
                ML[(obase + qrow) * 2 + 1] = lsum[m][r];
            }
        }
}

// ---------------- merge the two key-halves (log-sum-exp) -> fp16 Obf -------
__global__ __launch_bounds__(256) void flash_merge(const float* __restrict__ OP,
                                                   const float* __restrict__ ML,
                                                   unsigned short* __restrict__ Obf) {
    int row = blockIdx.x * 2 + (threadIdx.x >> 7);   // h*2048 + q
    int d   = threadIdx.x & 127;
    int h = row >> 11, q = row & 2047;
    size_t i0 = (size_t)h * S_LEN + q;
    size_t i1 = (size_t)(NHEAD + h) * S_LEN + q;
    float m0 = ML[i0 * 2], l0 = ML[i0 * 2 + 1];
    float m1 = ML[i1 * 2], l1 = ML[i1 * 2 + 1];
    float mf = fmaxf(m0, m1);
    float w0 = __expf(m0 - mf), w1 = __expf(m1 - mf);
    float inv = 1.f / (l0 * w0 + l1 * w1);
    float o = (OP[i0 * HD + d] * w0 + OP[i1 * HD + d] * w1) * inv;
    Obf[(size_t)q * HID + h * HD + d] = f2h(o);
}

// ---------------- launch ----------------
extern "C" void kernel_launch(void* const* d_in, const int* in_sizes, int n_in,
                              void* d_out, int out_size, void* d_ws, size_t ws_size,
                              hipStream_t stream) {
    const float* hs   = (const float*)d_in[0];
    const float* cosb = (const float*)d_in[1];
    const float* sinb = (const float*)d_in[2];
    const float* wq   = (const float*)d_in[3];
    const float* wk   = (const float*)d_in[4];
    const float* wv   = (const float*)d_in[5];
    const float* wo   = (const float*)d_in[6];
    float* out = (float*)d_out;
    char*  ws  = (char*)d_ws;

    // ws layout (phase-lifetime aliasing, ~134 MB):
    //  [0, 33.6M):     w_qk16 (dead after gemm1) -> Q16 | K16 | kbias
    //  [33.6, 100.7M): qk_f32 (dead after prep)  -> OP | ML
    //  [100.7M,...):   hs16 (->Obf after GEMMs) | w_v16 | w_o16 | Vt
    unsigned short* w_qk16 = (unsigned short*)(ws);
    unsigned short* Q16    = (unsigned short*)(ws);
    unsigned short* K16    = (unsigned short*)(ws + 8388608);
    float*          kbias  = (float*)(ws + 16777216);
    float*          qk_f32 = (float*)(ws + 33554432);
    float*          OP     = (float*)(ws + 33554432);             // aliases qk_f32
    float*          ML     = (float*)(ws + 33554432 + 33554432);
    unsigned short* hs16   = (unsigned short*)(ws + 100663296);
    unsigned short* Obf    = (unsigned short*)(ws + 100663296);   // aliases hs16
    unsigned short* w_v16  = (unsigned short*)(ws + 109051904);
    unsigned short* w_o16  = (unsigned short*)(ws + 117440512);
    unsigned short* Vt     = (unsigned short*)(ws + 125829120);

    {
        int n4 = (S_LEN * HID) / 4;
        cast_f16<<<(n4 + 255) / 256, 256, 0, stream>>>(hs, hs16, n4);
    }
    {
        int n4 = (4096 * K_HID) / 4;
        cast_f16<<<(n4 + 255) / 256, 256, 0, stream>>>(wq, w_qk16, n4);
        cast_f16<<<(n4 + 255) / 256, 256, 0, stream>>>(wk, w_qk16 + (size_t)4096 * K_HID, n4);
    }
    {
        int n4 = (HID * K_HID) / 4;
        cast_f16<<<(n4 + 255) / 256, 256, 0, stream>>>(wv, w_v16, n4);
        cast_f16<<<(n4 + 255) / 256, 256, 0, stream>>>(wo, w_o16, n4);
    }

    // QK projection, single fp16 -> fp32  [2048, 8192]
    gemm_nt_f16<false><<<dim3(64, 16), 256, 0, stream>>>(hs16, w_qk16, qk_f32,
                                                         S_LEN, NQK, K_HID);
    // V^T projection: Vt[d][s] = sum_k wv[d][k] * hs[s][k]  (fp16 out)
    gemm_nt_f16<true><<<dim3(16, 16), 256, 0, stream>>>(w_v16, hs16, Vt, HID, S_LEN, K_HID);
    // softplus / rsqrt / RoPE -> fp16 q̂,k̂ + CONSISTENT fp32 key bias
    prep_qk<<<(NHEAD * S_LEN) / 4, 256, 0, stream>>>(qk_f32, cosb, sinb,
                                                     Q16, K16, kbias);
    // flash attention (fp16 MFMA, key-split 2) -> partials
    flash_mfma<<<dim3(S_LEN / 128, NHEAD, 2), 256, 0, stream>>>(Q16, K16, Vt,
                                                                kbias, OP, ML);
    // merge halves -> fp16 attn_out
    flash_merge<<<(NHEAD * S_LEN) / 2, 256, 0, stream>>>(OP, ML, Obf);
    // output projection: out = Obf @ w_o^T (fp32 out)
    gemm_nt_f16<false><<<dim3(16, 16), 256, 0, stream>>>(Obf, w_o16, out, S_LEN, HID, K_HID);
}

// Round 7
// 443.523 us; speedup vs baseline: 2.7109x; 1.0925x over previous
//
#include <hip/hip_runtime.h>
#include <stdint.h>

// ---------------- problem constants ----------------
#define S_LEN 2048
#define HID   2048
#define NHEAD 16
#define HD    128     // head dim
#define NQK   8192    // concat q,k rows of [w_q; w_k]
#define K_HID 2048

typedef _Float16 f16x8 __attribute__((ext_vector_type(8)));
typedef float    f32x4 __attribute__((ext_vector_type(4)));

__device__ __forceinline__ unsigned short f2h(float f) {
    _Float16 h = (_Float16)f;                    // RNE
    union { _Float16 h; unsigned short u; } c; c.h = h;
    return c.u;
}
__device__ __forceinline__ float h2f(unsigned short b) {
    union { unsigned short u; _Float16 h; } c; c.u = b;
    return (float)c.h;
}
__device__ __forceinline__ float softplus_f(float x) {
    return (x > 20.f) ? x : log1pf(expf(x));
}
// async global->LDS, 16 B/lane; LDS dest = wave-uniform base + lane*16
__device__ __forceinline__ void gload_lds16(const unsigned short* g, unsigned short* l) {
    __builtin_amdgcn_global_load_lds(
        (const __attribute__((address_space(1))) unsigned int*)g,
        (__attribute__((address_space(3))) unsigned int*)l, 16, 0, 0);
}

// ---------------- fused cast fp32 -> fp16, 5 segments ----------------
// per block: 256 float4s. Block counts: hs 4096 | wq 8192 | wk 8192 | wv 4096 | wo 4096
__global__ __launch_bounds__(256) void cast5(const float* __restrict__ hs,
                                             const float* __restrict__ wq,
                                             const float* __restrict__ wk,
                                             const float* __restrict__ wv,
                                             const float* __restrict__ wo,
                                             unsigned short* __restrict__ hs16,
                                             unsigned short* __restrict__ wqk16,
                                             unsigned short* __restrict__ wv16,
                                             unsigned short* __restrict__ wo16) {
    int b = blockIdx.x;
    const float* src;
    unsigned short* dst;
    int i;
    if (b < 4096)       { src = hs; dst = hs16;                          i = b; }
    else if (b < 12288) { src = wq; dst = wqk16;                         i = b - 4096; }
    else if (b < 20480) { src = wk; dst = wqk16 + (size_t)4096 * K_HID;  i = b - 12288; }
    else if (b < 24576) { src = wv; dst = wv16;                          i = b - 20480; }
    else                { src = wo; dst = wo16;                          i = b - 24576; }
    int idx = i * 256 + threadIdx.x;
    float4 v = ((const float4*)src)[idx];
    ushort4 o;
    o.x = f2h(v.x); o.y = f2h(v.y); o.z = f2h(v.z); o.w = f2h(v.w);
    ((ushort4*)dst)[idx] = o;
}

// ---------------- fp16 NT GEMM: C[M,N] = A[M,K] * B[N,K]^T -----------------
// 128x128 tile, BK=32, 256 thr = 4 waves (2x2), 4x4 MFMA tiles/wave.
// m97-style staging: global_load_lds width=16 into UNPADDED [128][32] tiles.
// LDS budget check: A tile = 128x32 fp16 = 8 KB = 8 chunks (64 lanes x 16 B);
// each wave stages 2 chunks of A + 2 of B  (R6 bug: 16 chunks -> overflow).
// C/D layout: col = lane&15, row = (lane>>4)*4 + reg  (harness-verified)
template <bool OUT_F16>
__global__ __launch_bounds__(256) void gemm_nt_f16(const unsigned short* __restrict__ A,
                                                   const unsigned short* __restrict__ B,
                                                   void* __restrict__ Cv,
                                                   int M, int N, int Kd) {
    __shared__ __align__(16) unsigned short As[128 * 32];
    __shared__ __align__(16) unsigned short Bs[128 * 32];
    const int t    = threadIdx.x;
    const int m0   = blockIdx.y * 128;
    const int n0   = blockIdx.x * 128;
    const int wave = t >> 6;
    const int lane = t & 63;
    const int wm   = wave >> 1, wn = wave & 1;
    const int lrow = lane & 15, quad = lane >> 4;
    const int srow = lane >> 2;        // 0..15 within chunk
    const int scol = (lane & 3) * 8;   // 0,8,16,24

    f32x4 acc[4][4];
    for (int i = 0; i < 4; ++i)
        for (int j = 0; j < 4; ++j)
            acc[i][j] = (f32x4){0.f, 0.f, 0.f, 0.f};

    for (int k0 = 0; k0 < Kd; k0 += 32) {
        // chunk ch covers rows ch*16..+15; lane l -> row +l/4, col (l&3)*8
        for (int c = 0; c < 2; ++c) {
            int ch = wave * 2 + c;     // 0..7
            int row = ch * 16 + srow;  // 0..127
            gload_lds16(A + (size_t)(m0 + row) * Kd + k0 + scol, &As[ch * 512]);
            gload_lds16(B + (size_t)(n0 + row) * Kd + k0 + scol, &Bs[ch * 512]);
        }
        __syncthreads();

        f16x8 af[4], bfr[4];
        for (int tm = 0; tm < 4; ++tm)
            af[tm]  = *(const f16x8*)(&As[(wm * 64 + tm * 16 + lrow) * 32 + quad * 8]);
        for (int tn = 0; tn < 4; ++tn)
            bfr[tn] = *(const f16x8*)(&Bs[(wn * 64 + tn * 16 + lrow) * 32 + quad * 8]);
        for (int tm = 0; tm < 4; ++tm)
            for (int tn = 0; tn < 4; ++tn)
                acc[tm][tn] = __builtin_amdgcn_mfma_f32_16x16x32_f16(af[tm], bfr[tn], acc[tm][tn], 0, 0, 0);
        __syncthreads();
    }

    for (int tm = 0; tm < 4; ++tm)
        for (int tn = 0; tn < 4; ++tn) {
            int col = n0 + wn * 64 + tn * 16 + lrow;
            for (int r = 0; r < 4; ++r) {
                int row = m0 + wm * 64 + tm * 16 + quad * 4 + r;
                if (OUT_F16)
                    ((unsigned short*)Cv)[(size_t)row * N + col] = f2h(acc[tm][tn][r]);
                else
                    ((float*)Cv)[(size_t)row * N + col] = acc[tm][tn][r];
            }
        }
}

// ---------------- prep: softplus + rsqrt + RoPE -> fp16 q̂,k̂ ---------------
// CONSISTENCY: kbias computed from the fp16-ROUNDED k̂ (exact scores of a
// perturbed problem; q-side constants cancel in softmax exactly).
__global__ __launch_bounds__(256) void prep_qk(const float* __restrict__ qk,
                                               const float* __restrict__ cosb,
                                               const float* __restrict__ sinb,
                                               unsigned short* __restrict__ Q16,
                                               unsigned short* __restrict__ K16,
                                               float* __restrict__ kbias) {
    int gid  = blockIdx.x * 4 + (threadIdx.x >> 6);
    int lane = threadIdx.x & 63;
    int h = gid >> 11;
    int s = gid & 2047;
    int d1 = lane, d2 = lane + 64;
    const float* row = qk + (size_t)s * NQK;
    float c1 = cosb[s * HD + d1], c2 = cosb[s * HD + d2];
    float s1 = sinb[s * HD + d1], s2 = sinb[s * HD + d2];
    size_t ob = ((size_t)h * S_LEN + s) * HD;

    {   // Q side
        int base = h * 256;
        float mu1 = row[base + d1],            mu2 = row[base + d2];
        float sg1 = softplus_f(row[base + 128 + d1]) + 1e-4f;
        float sg2 = softplus_f(row[base + 128 + d2]) + 1e-4f;
        float w1 = mu1 * rsqrtf(sg1), w2 = mu2 * rsqrtf(sg2);
        float o1 = w1 * c1 - w2 * s1;
        float o2 = w2 * c2 + w1 * s2;
        Q16[ob + d1] = f2h(o1);
        Q16[ob + d2] = f2h(o2);
    }
    {   // K side + bias from ROUNDED k̂
        int base = 4096 + h * 256;
        float mu1 = row[base + d1],            mu2 = row[base + d2];
        float sg1 = softplus_f(row[base + 128 + d1]) + 1e-4f;
        float sg2 = softplus_f(row[base + 128 + d2]) + 1e-4f;
        float w1 = mu1 * rsqrtf(sg1), w2 = mu2 * rsqrtf(sg2);
        float o1 = w1 * c1 - w2 * s1;
        float o2 = w2 * c2 + w1 * s2;
        unsigned short k1 = f2h(o1), k2 = f2h(o2);
        K16[ob + d1] = k1; K16[ob + d2] = k2;
        float r1 = h2f(k1), r2 = h2f(k2);
        float part = r1 * r1 + r2 * r2 + logf(sg1) + logf(sg2);
        for (int off = 32; off > 0; off >>= 1) part += __shfl_down(part, off);
        if (lane == 0) kbias[(size_t)h * S_LEN + s] = -0.5f * part;
    }
}

// ---------------- flash attention, fp16 MFMA, key-split partials -----------
// Block 256 thr = 4 waves; Q-tile 128 (wave owns 32 queries = 2 m-frags);
// K-tile 64/iter; blockIdx.z = key-half (1024 keys each).
// K/V staged via global_load_lds, chunked: Khs[kk][64][32], Vts[kc][128][32];
// both tiles are 16 KB = exactly 16 chunks -> 4 chunks per wave each.
// l-sum deferred: per-lane partials, one butterfly at the end.
__global__ __launch_bounds__(256, 2) void flash_mfma(const unsigned short* __restrict__ Q16,
                                                     const unsigned short* __restrict__ K16,
                                                     const unsigned short* __restrict__ Vt,
                                                     const float* __restrict__ kbias,
                                                     float* __restrict__ OP,
                                                     float* __restrict__ ML) {
    constexpr int LV = 72;   // P row pad
    __shared__ __align__(16) unsigned short Khs[4 * 64 * 32];    // 16 KB
    __shared__ __align__(16) unsigned short Vts[2 * 128 * 32];   // 16 KB
    __shared__ __align__(16) unsigned short Ps[128 * LV];        // 18.4 KB
    __shared__ float kb[64];

    const int t    = threadIdx.x;
    const int h    = blockIdx.y;
    const int q0   = blockIdx.x * 128;
    const int kz   = blockIdx.z;
    const int wave = t >> 6;
    const int lane = t & 63;
    const int lrow = lane & 15, quad = lane >> 4;
    const int srow = lane >> 2;
    const int scol = (lane & 3) * 8;

    // Q fragments (2 m-tiles x 4 k-steps), registers for the whole kernel.
    f16x8 qf[2][4];
    for (int m = 0; m < 2; ++m) {
        size_t rb = ((size_t)h * S_LEN + q0 + wave * 32 + m * 16 + lrow) * HD;
        for (int kk = 0; kk < 4; ++kk)
            qf[m][kk] = *(const f16x8*)(Q16 + rb + kk * 32 + quad * 8);
    }

    float mrow[2][4], lsum[2][4];   // lsum = per-LANE partial (deferred reduce)
    f32x4 Ofr[2][8];
    for (int m = 0; m < 2; ++m)
        for (int r = 0; r < 4; ++r) { mrow[m][r] = -INFINITY; lsum[m][r] = 0.f; }
    for (int m = 0; m < 2; ++m)
        for (int d = 0; d < 8; ++d) Ofr[m][d] = (f32x4){0.f, 0.f, 0.f, 0.f};

    const int kbeg = kz * 1024;
    for (int k0 = kbeg; k0 < kbeg + 1024; k0 += 64) {
        {   // stage K (64 x 128 -> [kk][64][32]) and Vt (128 x 64 -> [kc][128][32])
            const unsigned short* kgb = K16 + ((size_t)h * S_LEN + k0) * HD;
            const unsigned short* vgb = Vt + ((size_t)h * HD) * S_LEN + k0;
            for (int c = 0; c < 4; ++c) {
                int ch = wave * 4 + c;                 // 0..15
                int kk = ch >> 2;                      // col-chunk 0..3
                int r  = (ch & 3) * 16 + srow;         // key row 0..63
                gload_lds16(kgb + (size_t)r * HD + kk * 32 + scol, &Khs[ch * 512]);
                int kc = ch >> 3;                      // key-chunk 0..1
                int r2 = (ch & 7) * 16 + srow;         // d row 0..127
                gload_lds16(vgb + (size_t)r2 * S_LEN + kc * 32 + scol, &Vts[ch * 512]);
            }
            if (t < 64) kb[t] = kbias[(size_t)h * S_LEN + k0 + t];
        }
        __syncthreads();

        // QK^T: 4 n-tiles (64 keys) x 4 k-steps x 2 m-tiles, fp16 single pass
        f32x4 sc[2][4];
        for (int m = 0; m < 2; ++m)
            for (int nt = 0; nt < 4; ++nt) sc[m][nt] = (f32x4){0.f, 0.f, 0.f, 0.f};
        for (int kk = 0; kk < 4; ++kk)
            for (int nt = 0; nt < 4; ++nt) {
                f16x8 khf = *(const f16x8*)(&Khs[kk * 2048 + (nt * 16 + lrow) * 32 + quad * 8]);
                sc[0][nt] = __builtin_amdgcn_mfma_f32_16x16x32_f16(qf[0][kk], khf, sc[0][nt], 0, 0, 0);
                sc[1][nt] = __builtin_amdgcn_mfma_f32_16x16x32_f16(qf[1][kk], khf, sc[1][nt], 0, 0, 0);
            }
        float kbn[4] = {kb[lrow], kb[16 + lrow], kb[32 + lrow], kb[48 + lrow]};

        // online softmax per (m, r); only the MAX needs a butterfly per iter
        for (int m = 0; m < 2; ++m)
            for (int r = 0; r < 4; ++r) {
                float s0 = sc[m][0][r] + kbn[0];
                float s1 = sc[m][1][r] + kbn[1];
                float s2 = sc[m][2][r] + kbn[2];
                float s3 = sc[m][3][r] + kbn[3];
                float mx = fmaxf(fmaxf(s0, s1), fmaxf(s2, s3));
                mx = fmaxf(mx, __shfl_xor(mx, 1));
                mx = fmaxf(mx, __shfl_xor(mx, 2));
                mx = fmaxf(mx, __shfl_xor(mx, 4));
                mx = fmaxf(mx, __shfl_xor(mx, 8));
                float mnew  = fmaxf(mrow[m][r], mx);
                float alpha = __expf(mrow[m][r] - mnew);
                mrow[m][r] = mnew;
                float p0 = __expf(s0 - mnew);
                float p1 = __expf(s1 - mnew);
                float p2 = __expf(s2 - mnew);
                float p3 = __expf(s3 - mnew);
                lsum[m][r] = lsum[m][r] * alpha + ((p0 + p1) + (p2 + p3));
                for (int d = 0; d < 8; ++d) Ofr[m][d][r] *= alpha;
                int prow = (wave * 32 + m * 16 + quad * 4 + r) * LV;
                Ps[prow + lrow]      = f2h(p0);
                Ps[prow + 16 + lrow] = f2h(p1);
                Ps[prow + 32 + lrow] = f2h(p2);
                Ps[prow + 48 + lrow] = f2h(p3);
            }

        // PV: A = P (wave-private rows), B = Vt; 2 key-chunks x 8 d-tiles
        for (int c = 0; c < 2; ++c) {
            f16x8 pa0 = *(const f16x8*)(&Ps[(wave * 32 + lrow) * LV + c * 32 + quad * 8]);
            f16x8 pa1 = *(const f16x8*)(&Ps[(wave * 32 + 16 + lrow) * LV + c * 32 + quad * 8]);
            for (int dt = 0; dt < 8; ++dt) {
                f16x8 vb = *(const f16x8*)(&Vts[c * 4096 + (dt * 16 + lrow) * 32 + quad * 8]);
                Ofr[0][dt] = __builtin_amdgcn_mfma_f32_16x16x32_f16(pa0, vb, Ofr[0][dt], 0, 0, 0);
                Ofr[1][dt] = __builtin_amdgcn_mfma_f32_16x16x32_f16(pa1, vb, Ofr[1][dt], 0, 0, 0);
            }
        }
        __syncthreads();
    }

    // deferred l reduction (4 shfl per row, once) + epilogue
    size_t obase = (size_t)(kz * NHEAD + h) * S_LEN;
    for (int m = 0; m < 2; ++m)
        for (int r = 0; r < 4; ++r) {
            float rs = lsum[m][r];
            rs += __shfl_xor(rs, 1);
            rs += __shfl_xor(rs, 2);
            rs += __shfl_xor(rs, 4);
            rs += __shfl_xor(rs, 8);
            int qrow = q0 + wave * 32 + m * 16 + quad * 4 + r;
            float* op = OP + (obase + qrow) * HD;
            for (int dt = 0; dt < 8; ++dt)
                op[dt * 16 + lrow] = Ofr[m][dt][r];
            if (lrow == 0) {
                ML[(obase + qrow) * 2]     = mrow[m][r];
                ML[(obase + qrow) * 2 + 1] = rs;
            }
        }
}

// ---------------- merge the two key-halves (log-sum-exp) -> fp16 Obf -------
__global__ __launch_bounds__(256) void flash_merge(const float* __restrict__ OP,
                                                   const float* __restrict__ ML,
                                                   unsigned short* __restrict__ Obf) {
    int row = blockIdx.x * 2 + (threadIdx.x >> 7);   // h*2048 + q
    int d   = threadIdx.x & 127;
    int h = row >> 11, q = row & 2047;
    size_t i0 = (size_t)h * S_LEN + q;
    size_t i1 = (size_t)(NHEAD + h) * S_LEN + q;
    float m0 = ML[i0 * 2], l0 = ML[i0 * 2 + 1];
    float m1 = ML[i1 * 2], l1 = ML[i1 * 2 + 1];
    float mf = fmaxf(m0, m1);
    float w0 = __expf(m0 - mf), w1 = __expf(m1 - mf);
    float inv = 1.f / (l0 * w0 + l1 * w1);
    float o = (OP[i0 * HD + d] * w0 + OP[i1 * HD + d] * w1) * inv;
    Obf[(size_t)q * HID + h * HD + d] = f2h(o);
}

// ---------------- launch ----------------
extern "C" void kernel_launch(void* const* d_in, const int* in_sizes, int n_in,
                              void* d_out, int out_size, void* d_ws, size_t ws_size,
                              hipStream_t stream) {
    const float* hs   = (const float*)d_in[0];
    const float* cosb = (const float*)d_in[1];
    const float* sinb = (const float*)d_in[2];
    const float* wq   = (const float*)d_in[3];
    const float* wk   = (const float*)d_in[4];
    const float* wv   = (const float*)d_in[5];
    const float* wo   = (const float*)d_in[6];
    float* out = (float*)d_out;
    char*  ws  = (char*)d_ws;

    // ws layout (phase-lifetime aliasing, ~134 MB):
    //  [0, 33.6M):     w_qk16 (dead after gemm1) -> Q16 | K16 | kbias
    //  [33.6, 100.7M): qk_f32 (dead after prep)  -> OP | ML
    //  [100.7M,...):   hs16 (->Obf after GEMMs) | w_v16 | w_o16 | Vt
    unsigned short* w_qk16 = (unsigned short*)(ws);
    unsigned short* Q16    = (unsigned short*)(ws);
    unsigned short* K16    = (unsigned short*)(ws + 8388608);
    float*          kbias  = (float*)(ws + 16777216);
    float*          qk_f32 = (float*)(ws + 33554432);
    float*          OP     = (float*)(ws + 33554432);             // aliases qk_f32
    float*          ML     = (float*)(ws + 33554432 + 33554432);
    unsigned short* hs16   = (unsigned short*)(ws + 100663296);
    unsigned short* Obf    = (unsigned short*)(ws + 100663296);   // aliases hs16
    unsigned short* w_v16  = (unsigned short*)(ws + 109051904);
    unsigned short* w_o16  = (unsigned short*)(ws + 117440512);
    unsigned short* Vt     = (unsigned short*)(ws + 125829120);

    // fused casts (5 segments, 28672 blocks)
    cast5<<<28672, 256, 0, stream>>>(hs, wq, wk, wv, wo, hs16, w_qk16, w_v16, w_o16);

    // QK projection, fp16 -> fp32  [2048, 8192]
    gemm_nt_f16<false><<<dim3(64, 16), 256, 0, stream>>>(hs16, w_qk16, qk_f32,
                                                         S_LEN, NQK, K_HID);
    // V^T projection: Vt[d][s] = sum_k wv[d][k] * hs[s][k]  (fp16 out)
    gemm_nt_f16<true><<<dim3(16, 16), 256, 0, stream>>>(w_v16, hs16, Vt, HID, S_LEN, K_HID);
    // softplus / rsqrt / RoPE -> fp16 q̂,k̂ + CONSISTENT fp32 key bias
    prep_qk<<<(NHEAD * S_LEN) / 4, 256, 0, stream>>>(qk_f32, cosb, sinb,
                                                     Q16, K16, kbias);
    // flash attention (fp16 MFMA, key-split 2) -> partials
    flash_mfma<<<dim3(S_LEN / 128, NHEAD, 2), 256, 0, stream>>>(Q16, K16, Vt,
                                                                kbias, OP, ML);
    // merge halves -> fp16 attn_out
    flash_merge<<<(NHEAD * S_LEN) / 2, 256, 0, stream>>>(OP, ML, Obf);
    // output projection: out = Obf @ w_o^T (fp32 out)
    gemm_nt_f16<false><<<dim3(16, 16), 256, 0, stream>>>(Obf, w_o16, out, S_LEN, HID, K_HID);
}

// Round 8
// 398.325 us; speedup vs baseline: 3.0185x; 1.1135x over previous
//
#include <hip/hip_runtime.h>
#include <stdint.h>

// ---------------- problem constants ----------------
#define S_LEN 2048
#define HID   2048
#define NHEAD 16
#define HD    128     // head dim
#define NQK   8192    // concat q,k rows of [w_q; w_k]
#define K_HID 2048

typedef _Float16 f16x8 __attribute__((ext_vector_type(8)));
typedef float    f32x4 __attribute__((ext_vector_type(4)));

__device__ __forceinline__ unsigned short f2h(float f) {
    _Float16 h = (_Float16)f;                    // RNE
    union { _Float16 h; unsigned short u; } c; c.h = h;
    return c.u;
}
__device__ __forceinline__ float h2f(unsigned short b) {
    union { unsigned short u; _Float16 h; } c; c.u = b;
    return (float)c.h;
}
__device__ __forceinline__ float softplus_f(float x) {
    return (x > 20.f) ? x : log1pf(expf(x));
}
// async global->LDS, 16 B/lane; LDS dest = wave-uniform base + lane*16
__device__ __forceinline__ void gload_lds16(const unsigned short* g, unsigned short* l) {
    __builtin_amdgcn_global_load_lds(
        (const __attribute__((address_space(1))) unsigned int*)g,
        (__attribute__((address_space(3))) unsigned int*)l, 16, 0, 0);
}

// ---------------- fused cast fp32 -> fp16, 5 segments ----------------
__global__ __launch_bounds__(256) void cast5(const float* __restrict__ hs,
                                             const float* __restrict__ wq,
                                             const float* __restrict__ wk,
                                             const float* __restrict__ wv,
                                             const float* __restrict__ wo,
                                             unsigned short* __restrict__ hs16,
                                             unsigned short* __restrict__ wqk16,
                                             unsigned short* __restrict__ wv16,
                                             unsigned short* __restrict__ wo16) {
    int b = blockIdx.x;
    const float* src;
    unsigned short* dst;
    int i;
    if (b < 4096)       { src = hs; dst = hs16;                          i = b; }
    else if (b < 12288) { src = wq; dst = wqk16;                         i = b - 4096; }
    else if (b < 20480) { src = wk; dst = wqk16 + (size_t)4096 * K_HID;  i = b - 12288; }
    else if (b < 24576) { src = wv; dst = wv16;                          i = b - 20480; }
    else                { src = wo; dst = wo16;                          i = b - 24576; }
    int idx = i * 256 + threadIdx.x;
    float4 v = ((const float4*)src)[idx];
    ushort4 o;
    o.x = f2h(v.x); o.y = f2h(v.y); o.z = f2h(v.z); o.w = f2h(v.w);
    ((ushort4*)dst)[idx] = o;
}

// ---------------- shared NT-GEMM body (fp16 in, fp16 or fp32 out) ----------
// 128x128 tile, BK=32, 4 waves (2x2), 4x4 MFMA tiles/wave; m97 staging.
// LDS budget: tile = 128x32 fp16 = 8 KB = 8 chunks; 2 chunks A + 2 B / wave.
// C/D layout: col = lane&15, row = (lane>>4)*4 + reg  (harness-verified)
template <bool OUT_F16>
__device__ __forceinline__ void gemm_body(const unsigned short* __restrict__ A,
                                          const unsigned short* __restrict__ B,
                                          void* __restrict__ Cv,
                                          int m0, int n0, int N,
                                          unsigned short* As, unsigned short* Bs) {
    const int t    = threadIdx.x;
    const int wave = t >> 6;
    const int lane = t & 63;
    const int wm   = wave >> 1, wn = wave & 1;
    const int lrow = lane & 15, quad = lane >> 4;
    const int srow = lane >> 2;
    const int scol = (lane & 3) * 8;

    f32x4 acc[4][4];
    for (int i = 0; i < 4; ++i)
        for (int j = 0; j < 4; ++j)
            acc[i][j] = (f32x4){0.f, 0.f, 0.f, 0.f};

    for (int k0 = 0; k0 < K_HID; k0 += 32) {
        for (int c = 0; c < 2; ++c) {
            int ch = wave * 2 + c;     // 0..7
            int row = ch * 16 + srow;  // 0..127
            gload_lds16(A + (size_t)(m0 + row) * K_HID + k0 + scol, &As[ch * 512]);
            gload_lds16(B + (size_t)(n0 + row) * K_HID + k0 + scol, &Bs[ch * 512]);
        }
        __syncthreads();

        f16x8 af[4], bfr[4];
        for (int tm = 0; tm < 4; ++tm)
            af[tm]  = *(const f16x8*)(&As[(wm * 64 + tm * 16 + lrow) * 32 + quad * 8]);
        for (int tn = 0; tn < 4; ++tn)
            bfr[tn] = *(const f16x8*)(&Bs[(wn * 64 + tn * 16 + lrow) * 32 + quad * 8]);
        for (int tm = 0; tm < 4; ++tm)
            for (int tn = 0; tn < 4; ++tn)
                acc[tm][tn] = __builtin_amdgcn_mfma_f32_16x16x32_f16(af[tm], bfr[tn], acc[tm][tn], 0, 0, 0);
        __syncthreads();
    }

    for (int tm = 0; tm < 4; ++tm)
        for (int tn = 0; tn < 4; ++tn) {
            int col = n0 + wn * 64 + tn * 16 + lrow;
            for (int r = 0; r < 4; ++r) {
                int row = m0 + wm * 64 + tm * 16 + quad * 4 + r;
                if (OUT_F16)
                    ((unsigned short*)Cv)[(size_t)row * N + col] = f2h(acc[tm][tn][r]);
                else
                    ((float*)Cv)[(size_t)row * N + col] = acc[tm][tn][r];
            }
        }
}

// fused launch: QK projection (1024 blocks) + V^T projection (256 blocks)
__global__ __launch_bounds__(256) void gemm_qkv(const unsigned short* __restrict__ hs16,
                                                const unsigned short* __restrict__ wqk16,
                                                const unsigned short* __restrict__ wv16,
                                                unsigned short* __restrict__ qk16,
                                                unsigned short* __restrict__ Vt) {
    __shared__ __align__(16) unsigned short As[128 * 32];
    __shared__ __align__(16) unsigned short Bs[128 * 32];
    int b = blockIdx.x;
    if (b < 1024) {  // QK: C[2048, 8192] = hs @ w_qk^T
        gemm_body<true>(hs16, wqk16, qk16, (b >> 6) * 128, (b & 63) * 128, NQK, As, Bs);
    } else {         // V^T: C[2048_d, 2048_s] = w_v @ hs^T
        b -= 1024;
        gemm_body<true>(wv16, hs16, Vt, (b >> 4) * 128, (b & 15) * 128, S_LEN, As, Bs);
    }
}

// plain single GEMM (O-projection, fp32 out)
template <bool OUT_F16>
__global__ __launch_bounds__(256) void gemm_nt_f16(const unsigned short* __restrict__ A,
                                                   const unsigned short* __restrict__ B,
                                                   void* __restrict__ Cv,
                                                   int M, int N, int Kd) {
    __shared__ __align__(16) unsigned short As[128 * 32];
    __shared__ __align__(16) unsigned short Bs[128 * 32];
    gemm_body<OUT_F16>(A, B, Cv, blockIdx.y * 128, blockIdx.x * 128, N, As, Bs);
}

// ---------------- prep: softplus + rsqrt + RoPE -> fp16 q̂,k̂ ---------------
// Reads fp16 qk projections. kbias computed from the fp16-ROUNDED k̂
// (exact scores of a perturbed problem; q-side constants cancel exactly).
__global__ __launch_bounds__(256) void prep_qk(const unsigned short* __restrict__ qk,
                                               const float* __restrict__ cosb,
                                               const float* __restrict__ sinb,
                                               unsigned short* __restrict__ Q16,
                                               unsigned short* __restrict__ K16,
                                               float* __restrict__ kbias) {
    int gid  = blockIdx.x * 4 + (threadIdx.x >> 6);
    int lane = threadIdx.x & 63;
    int h = gid >> 11;
    int s = gid & 2047;
    int d1 = lane, d2 = lane + 64;
    const unsigned short* row = qk + (size_t)s * NQK;
    float c1 = cosb[s * HD + d1], c2 = cosb[s * HD + d2];
    float s1 = sinb[s * HD + d1], s2 = sinb[s * HD + d2];
    size_t ob = ((size_t)h * S_LEN + s) * HD;

    {   // Q side
        int base = h * 256;
        float mu1 = h2f(row[base + d1]),       mu2 = h2f(row[base + d2]);
        float sg1 = softplus_f(h2f(row[base + 128 + d1])) + 1e-4f;
        float sg2 = softplus_f(h2f(row[base + 128 + d2])) + 1e-4f;
        float w1 = mu1 * rsqrtf(sg1), w2 = mu2 * rsqrtf(sg2);
        float o1 = w1 * c1 - w2 * s1;
        float o2 = w2 * c2 + w1 * s2;
        Q16[ob + d1] = f2h(o1);
        Q16[ob + d2] = f2h(o2);
    }
    {   // K side + bias from ROUNDED k̂
        int base = 4096 + h * 256;
        float mu1 = h2f(row[base + d1]),       mu2 = h2f(row[base + d2]);
        float sg1 = softplus_f(h2f(row[base + 128 + d1])) + 1e-4f;
        float sg2 = softplus_f(h2f(row[base + 128 + d2])) + 1e-4f;
        float w1 = mu1 * rsqrtf(sg1), w2 = mu2 * rsqrtf(sg2);
        float o1 = w1 * c1 - w2 * s1;
        float o2 = w2 * c2 + w1 * s2;
        unsigned short k1 = f2h(o1), k2 = f2h(o2);
        K16[ob + d1] = k1; K16[ob + d2] = k2;
        float r1 = h2f(k1), r2 = h2f(k2);
        float part = r1 * r1 + r2 * r2 + logf(sg1) + logf(sg2);
        for (int off = 32; off > 0; off >>= 1) part += __shfl_down(part, off);
        if (lane == 0) kbias[(size_t)h * S_LEN + s] = -0.5f * part;
    }
}

// ---------------- flash attention, fp16 MFMA, key-split partials -----------
// Block 256 thr = 4 waves; Q-tile 128 (wave owns 32 q = 2 m-frags);
// K-tile 64/iter; blockIdx.z = key-half. K/V via global_load_lds, chunked:
// Khs[kk][64][32], Vts[kc][128][32] (16 KB each = 16 chunks, 4/wave).
// Emits UNNORMALIZED O (fp16) + (m,l) -> merged by flash_merge.
__global__ __launch_bounds__(256, 2) void flash_mfma(const unsigned short* __restrict__ Q16,
                                                     const unsigned short* __restrict__ K16,
                                                     const unsigned short* __restrict__ Vt,
                                                     const float* __restrict__ kbias,
                                                     unsigned short* __restrict__ OP,
                                                     float* __restrict__ ML) {
    constexpr int LV = 72;   // P row pad
    __shared__ __align__(16) unsigned short Khs[4 * 64 * 32];    // 16 KB
    __shared__ __align__(16) unsigned short Vts[2 * 128 * 32];   // 16 KB
    __shared__ __align__(16) unsigned short Ps[128 * LV];        // 18.4 KB
    __shared__ float kb[64];

    const int t    = threadIdx.x;
    const int h    = blockIdx.y;
    const int q0   = blockIdx.x * 128;
    const int kz   = blockIdx.z;
    const int wave = t >> 6;
    const int lane = t & 63;
    const int lrow = lane & 15, quad = lane >> 4;
    const int srow = lane >> 2;
    const int scol = (lane & 3) * 8;

    f16x8 qf[2][4];
    for (int m = 0; m < 2; ++m) {
        size_t rb = ((size_t)h * S_LEN + q0 + wave * 32 + m * 16 + lrow) * HD;
        for (int kk = 0; kk < 4; ++kk)
            qf[m][kk] = *(const f16x8*)(Q16 + rb + kk * 32 + quad * 8);
    }

    float mrow[2][4], lsum[2][4];   // lsum = per-LANE partial (deferred reduce)
    f32x4 Ofr[2][8];
    for (int m = 0; m < 2; ++m)
        for (int r = 0; r < 4; ++r) { mrow[m][r] = -INFINITY; lsum[m][r] = 0.f; }
    for (int m = 0; m < 2; ++m)
        for (int d = 0; d < 8; ++d) Ofr[m][d] = (f32x4){0.f, 0.f, 0.f, 0.f};

    const int kbeg = kz * 1024;
    for (int k0 = kbeg; k0 < kbeg + 1024; k0 += 64) {
        {
            const unsigned short* kgb = K16 + ((size_t)h * S_LEN + k0) * HD;
            const unsigned short* vgb = Vt + ((size_t)h * HD) * S_LEN + k0;
            for (int c = 0; c < 4; ++c) {
                int ch = wave * 4 + c;                 // 0..15
                int kk = ch >> 2;
                int r  = (ch & 3) * 16 + srow;
                gload_lds16(kgb + (size_t)r * HD + kk * 32 + scol, &Khs[ch * 512]);
                int kc = ch >> 3;
                int r2 = (ch & 7) * 16 + srow;
                gload_lds16(vgb + (size_t)r2 * S_LEN + kc * 32 + scol, &Vts[ch * 512]);
            }
            if (t < 64) kb[t] = kbias[(size_t)h * S_LEN + k0 + t];
        }
        __syncthreads();

        f32x4 sc[2][4];
        for (int m = 0; m < 2; ++m)
            for (int nt = 0; nt < 4; ++nt) sc[m][nt] = (f32x4){0.f, 0.f, 0.f, 0.f};
        for (int kk = 0; kk < 4; ++kk)
            for (int nt = 0; nt < 4; ++nt) {
                f16x8 khf = *(const f16x8*)(&Khs[kk * 2048 + (nt * 16 + lrow) * 32 + quad * 8]);
                sc[0][nt] = __builtin_amdgcn_mfma_f32_16x16x32_f16(qf[0][kk], khf, sc[0][nt], 0, 0, 0);
                sc[1][nt] = __builtin_amdgcn_mfma_f32_16x16x32_f16(qf[1][kk], khf, sc[1][nt], 0, 0, 0);
            }
        float kbn[4] = {kb[lrow], kb[16 + lrow], kb[32 + lrow], kb[48 + lrow]};

        for (int m = 0; m < 2; ++m)
            for (int r = 0; r < 4; ++r) {
                float s0 = sc[m][0][r] + kbn[0];
                float s1 = sc[m][1][r] + kbn[1];
                float s2 = sc[m][2][r] + kbn[2];
                float s3 = sc[m][3][r] + kbn[3];
                float mx = fmaxf(fmaxf(s0, s1), fmaxf(s2, s3));
                mx = fmaxf(mx, __shfl_xor(mx, 1));
                mx = fmaxf(mx, __shfl_xor(mx, 2));
                mx = fmaxf(mx, __shfl_xor(mx, 4));
                mx = fmaxf(mx, __shfl_xor(mx, 8));
                float mnew  = fmaxf(mrow[m][r], mx);
                float alpha = __expf(mrow[m][r] - mnew);
                mrow[m][r] = mnew;
                float p0 = __expf(s0 - mnew);
                float p1 = __expf(s1 - mnew);
                float p2 = __expf(s2 - mnew);
                float p3 = __expf(s3 - mnew);
                lsum[m][r] = lsum[m][r] * alpha + ((p0 + p1) + (p2 + p3));
                for (int d = 0; d < 8; ++d) Ofr[m][d][r] *= alpha;
                int prow = (wave * 32 + m * 16 + quad * 4 + r) * LV;
                Ps[prow + lrow]      = f2h(p0);
                Ps[prow + 16 + lrow] = f2h(p1);
                Ps[prow + 32 + lrow] = f2h(p2);
                Ps[prow + 48 + lrow] = f2h(p3);
            }

        for (int c = 0; c < 2; ++c) {
            f16x8 pa0 = *(const f16x8*)(&Ps[(wave * 32 + lrow) * LV + c * 32 + quad * 8]);
            f16x8 pa1 = *(const f16x8*)(&Ps[(wave * 32 + 16 + lrow) * LV + c * 32 + quad * 8]);
            for (int dt = 0; dt < 8; ++dt) {
                f16x8 vb = *(const f16x8*)(&Vts[c * 4096 + (dt * 16 + lrow) * 32 + quad * 8]);
                Ofr[0][dt] = __builtin_amdgcn_mfma_f32_16x16x32_f16(pa0, vb, Ofr[0][dt], 0, 0, 0);
                Ofr[1][dt] = __builtin_amdgcn_mfma_f32_16x16x32_f16(pa1, vb, Ofr[1][dt], 0, 0, 0);
            }
        }
        __syncthreads();
    }

    // deferred l reduction + epilogue (fp16 partials; |O| <= l*|v| < 6e4)
    size_t obase = (size_t)(kz * NHEAD + h) * S_LEN;
    for (int m = 0; m < 2; ++m)
        for (int r = 0; r < 4; ++r) {
            float rs = lsum[m][r];
            rs += __shfl_xor(rs, 1);
            rs += __shfl_xor(rs, 2);
            rs += __shfl_xor(rs, 4);
            rs += __shfl_xor(rs, 8);
            int qrow = q0 + wave * 32 + m * 16 + quad * 4 + r;
            unsigned short* op = OP + (obase + qrow) * HD;
            for (int dt = 0; dt < 8; ++dt)
                op[dt * 16 + lrow] = f2h(Ofr[m][dt][r]);
            if (lrow == 0) {
                ML[(obase + qrow) * 2]     = mrow[m][r];
                ML[(obase + qrow) * 2 + 1] = rs;
            }
        }
}

// ---------------- merge the two key-halves (log-sum-exp) -> fp16 Obf -------
__global__ __launch_bounds__(256) void flash_merge(const unsigned short* __restrict__ OP,
                                                   const float* __restrict__ ML,
                                                   unsigned short* __restrict__ Obf) {
    int row = blockIdx.x * 2 + (threadIdx.x >> 7);   // h*2048 + q
    int d   = threadIdx.x & 127;
    int h = row >> 11, q = row & 2047;
    size_t i0 = (size_t)h * S_LEN + q;
    size_t i1 = (size_t)(NHEAD + h) * S_LEN + q;
    float m0 = ML[i0 * 2], l0 = ML[i0 * 2 + 1];
    float m1 = ML[i1 * 2], l1 = ML[i1 * 2 + 1];
    float mf = fmaxf(m0, m1);
    float w0 = __expf(m0 - mf), w1 = __expf(m1 - mf);
    float inv = 1.f / (l0 * w0 + l1 * w1);
    float o = (h2f(OP[i0 * HD + d]) * w0 + h2f(OP[i1 * HD + d]) * w1) * inv;
    Obf[(size_t)q * HID + h * HD + d] = f2h(o);
}

// ---------------- launch ----------------
extern "C" void kernel_launch(void* const* d_in, const int* in_sizes, int n_in,
                              void* d_out, int out_size, void* d_ws, size_t ws_size,
                              hipStream_t stream) {
    const float* hs   = (const float*)d_in[0];
    const float* cosb = (const float*)d_in[1];
    const float* sinb = (const float*)d_in[2];
    const float* wq   = (const float*)d_in[3];
    const float* wk   = (const float*)d_in[4];
    const float* wv   = (const float*)d_in[5];
    const float* wo   = (const float*)d_in[6];
    float* out = (float*)d_out;
    char*  ws  = (char*)d_ws;

    // ws layout (phase-lifetime aliasing, ~101 MB):
    //  [0, 33.6M):     w_qk16 (dead after gemm_qkv) -> Q16 | K16 | kbias
    //  [33.6, 67.1M):  qk16 fp16 (dead after prep)  -> OP fp16 | ML
    //  [67.1M,...):    hs16 (->Obf) | w_v16 | w_o16 | Vt
    unsigned short* w_qk16 = (unsigned short*)(ws);
    unsigned short* Q16    = (unsigned short*)(ws);
    unsigned short* K16    = (unsigned short*)(ws + 8388608);
    float*          kbias  = (float*)(ws + 16777216);
    unsigned short* qk16   = (unsigned short*)(ws + 33554432);
    unsigned short* OP     = (unsigned short*)(ws + 33554432);    // aliases qk16
    float*          ML     = (float*)(ws + 50331648);
    unsigned short* hs16   = (unsigned short*)(ws + 67108864);
    unsigned short* Obf    = (unsigned short*)(ws + 67108864);    // aliases hs16
    unsigned short* w_v16  = (unsigned short*)(ws + 75497472);
    unsigned short* w_o16  = (unsigned short*)(ws + 83886080);
    unsigned short* Vt     = (unsigned short*)(ws + 92274688);

    // fused casts (5 segments, 28672 blocks)
    cast5<<<28672, 256, 0, stream>>>(hs, wq, wk, wv, wo, hs16, w_qk16, w_v16, w_o16);

    // fused QK projection [2048,8192] + V^T projection [2048,2048] (fp16 out)
    gemm_qkv<<<1280, 256, 0, stream>>>(hs16, w_qk16, w_v16, qk16, Vt);

    // softplus / rsqrt / RoPE -> fp16 q̂,k̂ + CONSISTENT fp32 key bias
    prep_qk<<<(NHEAD * S_LEN) / 4, 256, 0, stream>>>(qk16, cosb, sinb,
                                                     Q16, K16, kbias);
    // flash attention (fp16 MFMA, key-split 2) -> fp16 partials
    flash_mfma<<<dim3(S_LEN / 128, NHEAD, 2), 256, 0, stream>>>(Q16, K16, Vt,
                                                                kbias, OP, ML);
    // merge halves -> fp16 attn_out
    flash_merge<<<(NHEAD * S_LEN) / 2, 256, 0, stream>>>(OP, ML, Obf);
    // output projection: out = Obf @ w_o^T (fp32 out)
    gemm_nt_f16<false><<<dim3(16, 16), 256, 0, stream>>>(Obf, w_o16, out, S_LEN, HID, K_HID);
}